// Round 1
// baseline (804.020 us; speedup 1.0000x reference)
//
#include <hip/hip_runtime.h>
#include <hip/hip_bf16.h>
#include <math.h>

// Problem constants (B=2, L=1024, d_model=512, d_inner=1024, H=8, N=16, hd=128,
// dt_rank=32, out_dim=560). T = B*L = 2048 tokens.
//
// Pipeline:
//  1) gemm_nt: xz[T,2048]   = x[T,512]    @ W_in[2048,512]^T
//  2) conv_silu: xc[T,1024] = silu(causal_dwconv(xz[:, :1024]))
//  3) gemm_nt: proj[T,560]  = xc[T,1024]  @ W_x[560,1024]^T
//  4) delta_k: delta[T,1024]= softplus(proj[:, :32] @ W_dt^T + b_dt)
//  5) scan_k : complex SSM scan over L, fused y + D*xc, * silu(z) epilogue
//  6) gemm_nt: out[T,512]   = ygated[T,1024] @ W_out[512,1024]^T

// ---------------------------------------------------------------------------
// Generic f32 GEMM: C[M,N] = A[M,K] * W[N,K]^T  (both row-major).
// 64x64 tile per 256-thread block, 4x4 per thread, BK=16, LDS-staged.
// M must be a multiple of 64 (true here: M=2048); N is guarded.
// ---------------------------------------------------------------------------
__global__ __launch_bounds__(256)
void gemm_nt_k(const float* __restrict__ A, const float* __restrict__ W,
               float* __restrict__ C, int N, int K) {
  __shared__ __align__(16) float As[16][68];  // [k][m], +4 pad keeps float4 alignment
  __shared__ __align__(16) float Ws[16][68];  // [k][n]
  const int tid  = threadIdx.x;
  const int m0   = blockIdx.y * 64;
  const int n0   = blockIdx.x * 64;
  const int tx   = tid & 15;        // n sub-tile
  const int ty   = tid >> 4;        // m sub-tile
  const int lrow = tid >> 2;        // 0..63 : tile row loaded by this thread
  const int lcol = (tid & 3) << 2;  // 0,4,8,12 : k offset (float4)

  float acc[4][4] = {{0.f, 0.f, 0.f, 0.f}, {0.f, 0.f, 0.f, 0.f},
                     {0.f, 0.f, 0.f, 0.f}, {0.f, 0.f, 0.f, 0.f}};

  for (int k0 = 0; k0 < K; k0 += 16) {
    const float4 a4 =
        *reinterpret_cast<const float4*>(&A[(size_t)(m0 + lrow) * K + k0 + lcol]);
    float4 w4 = make_float4(0.f, 0.f, 0.f, 0.f);
    const int wrow = n0 + lrow;
    if (wrow < N)
      w4 = *reinterpret_cast<const float4*>(&W[(size_t)wrow * K + k0 + lcol]);

    __syncthreads();  // previous iteration's readers done
    As[lcol + 0][lrow] = a4.x; As[lcol + 1][lrow] = a4.y;
    As[lcol + 2][lrow] = a4.z; As[lcol + 3][lrow] = a4.w;
    Ws[lcol + 0][lrow] = w4.x; Ws[lcol + 1][lrow] = w4.y;
    Ws[lcol + 2][lrow] = w4.z; Ws[lcol + 3][lrow] = w4.w;
    __syncthreads();

#pragma unroll
    for (int k = 0; k < 16; ++k) {
      const float4 av = *reinterpret_cast<const float4*>(&As[k][ty << 2]);
      const float4 wv = *reinterpret_cast<const float4*>(&Ws[k][tx << 2]);
      acc[0][0] += av.x * wv.x; acc[0][1] += av.x * wv.y;
      acc[0][2] += av.x * wv.z; acc[0][3] += av.x * wv.w;
      acc[1][0] += av.y * wv.x; acc[1][1] += av.y * wv.y;
      acc[1][2] += av.y * wv.z; acc[1][3] += av.y * wv.w;
      acc[2][0] += av.z * wv.x; acc[2][1] += av.z * wv.y;
      acc[2][2] += av.z * wv.z; acc[2][3] += av.z * wv.w;
      acc[3][0] += av.w * wv.x; acc[3][1] += av.w * wv.y;
      acc[3][2] += av.w * wv.z; acc[3][3] += av.w * wv.w;
    }
  }

#pragma unroll
  for (int i = 0; i < 4; ++i) {
    const int m = m0 + (ty << 2) + i;
#pragma unroll
    for (int j = 0; j < 4; ++j) {
      const int nn = n0 + (tx << 2) + j;
      if (nn < N) C[(size_t)m * N + nn] = acc[i][j];
    }
  }
}

// ---------------------------------------------------------------------------
// Causal depthwise conv (K=3) + silu.  xc[t,c] = silu(b_c + sum_k w[c,k]*xp[l+k-2,c])
// One thread per (t,c); c is the fast index -> coalesced.
// ---------------------------------------------------------------------------
__global__ __launch_bounds__(256)
void conv_silu_k(const float* __restrict__ xz, const float* __restrict__ conv_w,
                 const float* __restrict__ conv_b, float* __restrict__ xc) {
  const int idx = blockIdx.x * 256 + threadIdx.x;  // T*1024 total
  const int c = idx & 1023;
  const int t = idx >> 10;
  const int l = t & 1023;  // position within batch (L=1024)
  const float* xp = xz + (size_t)t * 2048 + c;  // x_proj = xz[:, :1024]
  float acc = conv_b[c];
  const float w0 = conv_w[c * 3 + 0];
  const float w1 = conv_w[c * 3 + 1];
  const float w2 = conv_w[c * 3 + 2];
  acc += w2 * xp[0];
  if (l >= 1) acc += w1 * xp[-2048];
  if (l >= 2) acc += w0 * xp[-2 * 2048];
  xc[idx] = acc / (1.f + __expf(-acc));  // silu
}

// ---------------------------------------------------------------------------
// delta[t,c] = softplus( proj[t,0:32] . W_dt[c,0:32] + b_dt[c] )
// ---------------------------------------------------------------------------
__global__ __launch_bounds__(256)
void delta_k(const float* __restrict__ proj, const float* __restrict__ W_dt,
             const float* __restrict__ b_dt, float* __restrict__ delta) {
  const int idx = blockIdx.x * 256 + threadIdx.x;  // T*1024 total
  const int c = idx & 1023;
  const int t = idx >> 10;
  const float* pr = proj + (size_t)t * 560;
  const float* w = W_dt + c * 32;
  float acc = b_dt[c];
#pragma unroll
  for (int r = 0; r < 32; ++r) acc += pr[r] * w[r];
  // stable softplus: max(x,0) + log1p(exp(-|x|))
  delta[idx] = fmaxf(acc, 0.f) + log1pf(__expf(-fabsf(acc)));
}

// ---------------------------------------------------------------------------
// Complex SSM scan.  One thread per (b,h,d,n) channel, sequential over L.
// Block = 128 threads = 8 d-values x 16 n.  Grid = B*H*(128/8) = 256 blocks.
// State (h_re,h_im) and previous Bx kept in registers; next-step operands
// prefetched one iteration ahead.  Epilogue (n==0 lane): y + D*xc, * silu(z).
// ygated may alias delta: all 16 n-lanes of a group (same wave) read
// delta[t,c] before the lane-0 write to the same address in that iteration.
// ---------------------------------------------------------------------------
__global__ __launch_bounds__(128)
void scan_k(const float* __restrict__ xz, const float* __restrict__ xc,
            const float* __restrict__ proj, const float* __restrict__ delta,
            const float* __restrict__ A_log, const float* __restrict__ A_imag,
            const float* __restrict__ D_param, float* __restrict__ ygated) {
  const int blk  = blockIdx.x;
  const int dblk = blk & 15;        // 16 chunks of 8 d each
  const int h    = (blk >> 4) & 7;
  const int b    = blk >> 7;
  const int tid  = threadIdx.x;
  const int n    = tid & 15;
  const int dd   = tid >> 4;        // 0..7
  const int d    = dblk * 8 + dd;
  const int c    = h * 128 + d;

  const float Are = -__expf(A_log[h * 16 + n]);
  const float Aim = A_imag[h * 16 + n];
  const float Dc  = D_param[c];

  float hr = 0.f, hi = 0.f, bxpr = 0.f, bxpi = 0.f;

  int t = b * 1024;
  // prefetch l = 0
  float dv, xv, brv, biv, crv, civ, lgr, egr, zv;
  {
    const float* pr = proj + (size_t)t * 560;
    dv  = delta[(size_t)t * 1024 + c];
    xv  = xc[(size_t)t * 1024 + c];
    brv = pr[32  + h * 16 + n];
    biv = pr[160 + h * 16 + n];
    crv = pr[288 + h * 16 + n];
    civ = pr[416 + h * 16 + n];
    lgr = pr[544 + h];
    egr = pr[552 + h];
    zv  = xz[(size_t)t * 2048 + 1024 + c];
  }

  for (int l = 0; l < 1024; ++l, ++t) {
    float dv2 = 0.f, xv2 = 0.f, brv2 = 0.f, biv2 = 0.f, crv2 = 0.f,
          civ2 = 0.f, lgr2 = 0.f, egr2 = 0.f, zv2 = 0.f;
    if (l < 1023) {  // prefetch next step
      const float* pr = proj + (size_t)(t + 1) * 560;
      dv2  = delta[(size_t)(t + 1) * 1024 + c];
      xv2  = xc[(size_t)(t + 1) * 1024 + c];
      brv2 = pr[32  + h * 16 + n];
      biv2 = pr[160 + h * 16 + n];
      crv2 = pr[288 + h * 16 + n];
      civ2 = pr[416 + h * 16 + n];
      lgr2 = pr[544 + h];
      egr2 = pr[552 + h];
      zv2  = xz[(size_t)(t + 1) * 2048 + 1024 + c];
    }

    // gates
    const float lg = 1.f / (1.f + __expf(-lgr));
    const float eg = 1.f / (1.f + __expf(-egr));
    // alpha = exp(clip(dv*Are)) * (cos(dv*Aim), sin(dv*Aim))
    float dtre = dv * Are;
    dtre = fminf(fmaxf(dtre, -20.f), 20.f);
    const float dtim = dv * Aim;
    const float mag = __expf(dtre);
    float s, co;
    __sincosf(dtim, &s, &co);
    const float are = mag * co, aim = mag * s;
    // Bx (current)
    const float bxr = xv * brv, bxi = xv * biv;
    // u = (1-lg)*dv*alpha * Bx_prev  +  lg*dv*eg * Bx
    const float betas = (1.f - lg) * dv;
    const float gam = lg * dv * eg;
    const float ure = betas * (are * bxpr - aim * bxpi) + gam * bxr;
    const float uim = betas * (are * bxpi + aim * bxpr) + gam * bxi;
    // h = alpha * h + u
    const float nhr = are * hr - aim * hi + ure;
    const float nhi = are * hi + aim * hr + uim;
    hr = nhr; hi = nhi;
    bxpr = bxr; bxpi = bxi;

    // y contribution and reduce over n (low 4 lane bits)
    float y = hr * crv + hi * civ;
    y += __shfl_xor(y, 1);
    y += __shfl_xor(y, 2);
    y += __shfl_xor(y, 4);
    y += __shfl_xor(y, 8);

    if (n == 0) {
      const float yd = y + Dc * xv;
      const float g = zv / (1.f + __expf(-zv));  // silu(z)
      ygated[(size_t)t * 1024 + c] = yd * g;
    }

    dv = dv2; xv = xv2; brv = brv2; biv = biv2; crv = crv2; civ = civ2;
    lgr = lgr2; egr = egr2; zv = zv2;
  }
}

// ---------------------------------------------------------------------------
extern "C" void kernel_launch(void* const* d_in, const int* in_sizes, int n_in,
                              void* d_out, int out_size, void* d_ws, size_t ws_size,
                              hipStream_t stream) {
  (void)in_sizes; (void)n_in; (void)out_size; (void)ws_size;
  const float* x       = (const float*)d_in[0];
  const float* W_in    = (const float*)d_in[1];
  const float* conv_w  = (const float*)d_in[2];
  const float* conv_b  = (const float*)d_in[3];
  const float* W_x     = (const float*)d_in[4];
  const float* W_dt    = (const float*)d_in[5];
  const float* b_dt    = (const float*)d_in[6];
  const float* A_log   = (const float*)d_in[7];
  const float* A_imag  = (const float*)d_in[8];
  const float* D_param = (const float*)d_in[9];
  const float* W_out   = (const float*)d_in[10];
  float* out = (float*)d_out;

  // workspace layout (floats): xz[4194304] xc[2097152] proj[1146880] delta[2097152]
  float* ws    = (float*)d_ws;
  float* xz    = ws;                          // T x 2048
  float* xc    = xz + (size_t)2048 * 2048;    // T x 1024
  float* proj  = xc + (size_t)2048 * 1024;    // T x 560
  float* delta = proj + (size_t)2048 * 560;   // T x 1024
  float* ygated = delta;                      // alias (safe; see scan_k comment)

  // 1) xz = x @ W_in^T        (M=2048, N=2048, K=512)
  gemm_nt_k<<<dim3(32, 32), dim3(256), 0, stream>>>(x, W_in, xz, 2048, 512);
  // 2) xc = silu(dwconv(x_proj))
  conv_silu_k<<<dim3(8192), dim3(256), 0, stream>>>(xz, conv_w, conv_b, xc);
  // 3) proj = xc @ W_x^T      (M=2048, N=560, K=1024)
  gemm_nt_k<<<dim3(9, 32), dim3(256), 0, stream>>>(xc, W_x, proj, 560, 1024);
  // 4) delta = softplus(proj[:, :32] @ W_dt^T + b_dt)
  delta_k<<<dim3(8192), dim3(256), 0, stream>>>(proj, W_dt, b_dt, delta);
  // 5) scan + fused epilogue -> ygated
  scan_k<<<dim3(256), dim3(128), 0, stream>>>(xz, xc, proj, delta, A_log, A_imag,
                                              D_param, ygated);
  // 6) out = ygated @ W_out^T (M=2048, N=512, K=1024)
  gemm_nt_k<<<dim3(8, 32), dim3(256), 0, stream>>>(ygated, W_out, out, 512, 1024);
}

// Round 2
// 418.880 us; speedup vs baseline: 1.9195x; 1.9195x over previous
//
#include <hip/hip_runtime.h>
#include <hip/hip_bf16.h>
#include <math.h>

// Problem constants (B=2, L=1024, d_model=512, d_inner=1024, H=8, N=16, hd=128,
// dt_rank=32, out_dim=560). T = B*L = 2048 tokens.
//
// Pipeline:
//  1) gemm_nt: xz[T,2048]   = x[T,512]    @ W_in[2048,512]^T
//  2) conv_silu: xc[T,1024] = silu(causal_dwconv(xz[:, :1024]))
//  3) gemm_nt: proj[T,560]  = xc[T,1024]  @ W_x[560,1024]^T
//  4) delta_k: delta[T,1024]= softplus(proj[:, :32] @ W_dt^T + b_dt)
//  5) chunked complex scan (3 kernels, chunk=64, 16 chunks/seq):
//       part1: per-chunk cumulative alpha-product + zero-init end state
//       part2: 16-step scan over chunk summaries -> per-chunk carry-in
//       part3: re-run chunk from carry-in, y + D*xc, * silu(z) -> ygated
//  6) gemm_nt: out[T,512]   = ygated[T,1024] @ W_out[512,1024]^T

// ---------------------------------------------------------------------------
// Generic f32 GEMM: C[M,N] = A[M,K] * W[N,K]^T  (both row-major).
// 64x64 tile per 256-thread block, 4x4 per thread, BK=16, LDS-staged.
// ---------------------------------------------------------------------------
__global__ __launch_bounds__(256)
void gemm_nt_k(const float* __restrict__ A, const float* __restrict__ W,
               float* __restrict__ C, int N, int K) {
  __shared__ __align__(16) float As[16][68];
  __shared__ __align__(16) float Ws[16][68];
  const int tid  = threadIdx.x;
  const int m0   = blockIdx.y * 64;
  const int n0   = blockIdx.x * 64;
  const int tx   = tid & 15;
  const int ty   = tid >> 4;
  const int lrow = tid >> 2;
  const int lcol = (tid & 3) << 2;

  float acc[4][4] = {{0.f, 0.f, 0.f, 0.f}, {0.f, 0.f, 0.f, 0.f},
                     {0.f, 0.f, 0.f, 0.f}, {0.f, 0.f, 0.f, 0.f}};

  for (int k0 = 0; k0 < K; k0 += 16) {
    const float4 a4 =
        *reinterpret_cast<const float4*>(&A[(size_t)(m0 + lrow) * K + k0 + lcol]);
    float4 w4 = make_float4(0.f, 0.f, 0.f, 0.f);
    const int wrow = n0 + lrow;
    if (wrow < N)
      w4 = *reinterpret_cast<const float4*>(&W[(size_t)wrow * K + k0 + lcol]);

    __syncthreads();
    As[lcol + 0][lrow] = a4.x; As[lcol + 1][lrow] = a4.y;
    As[lcol + 2][lrow] = a4.z; As[lcol + 3][lrow] = a4.w;
    Ws[lcol + 0][lrow] = w4.x; Ws[lcol + 1][lrow] = w4.y;
    Ws[lcol + 2][lrow] = w4.z; Ws[lcol + 3][lrow] = w4.w;
    __syncthreads();

#pragma unroll
    for (int k = 0; k < 16; ++k) {
      const float4 av = *reinterpret_cast<const float4*>(&As[k][ty << 2]);
      const float4 wv = *reinterpret_cast<const float4*>(&Ws[k][tx << 2]);
      acc[0][0] += av.x * wv.x; acc[0][1] += av.x * wv.y;
      acc[0][2] += av.x * wv.z; acc[0][3] += av.x * wv.w;
      acc[1][0] += av.y * wv.x; acc[1][1] += av.y * wv.y;
      acc[1][2] += av.y * wv.z; acc[1][3] += av.y * wv.w;
      acc[2][0] += av.z * wv.x; acc[2][1] += av.z * wv.y;
      acc[2][2] += av.z * wv.z; acc[2][3] += av.z * wv.w;
      acc[3][0] += av.w * wv.x; acc[3][1] += av.w * wv.y;
      acc[3][2] += av.w * wv.z; acc[3][3] += av.w * wv.w;
    }
  }

#pragma unroll
  for (int i = 0; i < 4; ++i) {
    const int m = m0 + (ty << 2) + i;
#pragma unroll
    for (int j = 0; j < 4; ++j) {
      const int nn = n0 + (tx << 2) + j;
      if (nn < N) C[(size_t)m * N + nn] = acc[i][j];
    }
  }
}

// ---------------------------------------------------------------------------
// Causal depthwise conv (K=3) + silu.
// ---------------------------------------------------------------------------
__global__ __launch_bounds__(256)
void conv_silu_k(const float* __restrict__ xz, const float* __restrict__ conv_w,
                 const float* __restrict__ conv_b, float* __restrict__ xc) {
  const int idx = blockIdx.x * 256 + threadIdx.x;
  const int c = idx & 1023;
  const int t = idx >> 10;
  const int l = t & 1023;
  const float* xp = xz + (size_t)t * 2048 + c;
  float acc = conv_b[c];
  const float w0 = conv_w[c * 3 + 0];
  const float w1 = conv_w[c * 3 + 1];
  const float w2 = conv_w[c * 3 + 2];
  acc += w2 * xp[0];
  if (l >= 1) acc += w1 * xp[-2048];
  if (l >= 2) acc += w0 * xp[-2 * 2048];
  xc[idx] = acc / (1.f + __expf(-acc));
}

// ---------------------------------------------------------------------------
// delta[t,c] = softplus( proj[t,0:32] . W_dt[c,0:32] + b_dt[c] )
// ---------------------------------------------------------------------------
__global__ __launch_bounds__(256)
void delta_k(const float* __restrict__ proj, const float* __restrict__ W_dt,
             const float* __restrict__ b_dt, float* __restrict__ delta) {
  const int idx = blockIdx.x * 256 + threadIdx.x;
  const int c = idx & 1023;
  const int t = idx >> 10;
  const float* pr = proj + (size_t)t * 560;
  const float* w = W_dt + c * 32;
  float acc = b_dt[c];
#pragma unroll
  for (int r = 0; r < 32; ++r) acc += pr[r] * w[r];
  delta[idx] = fmaxf(acc, 0.f) + log1pf(__expf(-fabsf(acc)));
}

// ---------------------------------------------------------------------------
// Chunked scan.  gid bits: [b:1][chunk:4][h:3][d:7][n:4] -> 524288 threads.
// Per-step recurrence (shared by part1/part3):
//   alpha = exp(clip(dv*Are))*(cos,sin)(dv*Aim)
//   u     = (1-lg)*dv*alpha*Bx_prev + lg*dv*eg*Bx
//   h     = alpha*h + u
// ---------------------------------------------------------------------------
#define SCAN_STEP()                                                        \
  const float lg = 1.f / (1.f + __expf(-lgr));                             \
  const float eg = 1.f / (1.f + __expf(-egr));                             \
  const float dtre = fminf(fmaxf(dv * Are, -20.f), 20.f);                  \
  const float mag = __expf(dtre);                                          \
  float sn, co;                                                            \
  __sincosf(dv * Aim, &sn, &co);                                           \
  const float are = mag * co, aim = mag * sn;                              \
  const float bxr = xv * brv, bxi = xv * biv;                              \
  const float betas = (1.f - lg) * dv;                                     \
  const float gam = lg * dv * eg;                                          \
  const float ure = betas * (are * bxpr - aim * bxpi) + gam * bxr;         \
  const float uim = betas * (are * bxpi + aim * bxpr) + gam * bxi;         \
  const float nhr = are * hr - aim * hi + ure;                             \
  const float nhi = are * hi + aim * hr + uim;                             \
  hr = nhr; hi = nhi;                                                      \
  bxpr = bxr; bxpi = bxi;

__global__ __launch_bounds__(256)
void scan_part1_k(const float* __restrict__ xc, const float* __restrict__ proj,
                  const float* __restrict__ delta, const float* __restrict__ A_log,
                  const float* __restrict__ A_imag, float4* __restrict__ csum) {
  const int gid = blockIdx.x * 256 + threadIdx.x;
  const int n  = gid & 15;
  const int d  = (gid >> 4) & 127;
  const int h  = (gid >> 11) & 7;
  const int ck = (gid >> 14) & 15;
  const int b  = gid >> 18;
  const int c  = h * 128 + d;

  const float Are = -__expf(A_log[h * 16 + n]);
  const float Aim = A_imag[h * 16 + n];

  int t = b * 1024 + ck * 64;
  float bxpr = 0.f, bxpi = 0.f;
  if (ck > 0) {
    const float xv = xc[(size_t)(t - 1) * 1024 + c];
    bxpr = xv * proj[(size_t)(t - 1) * 560 + 32 + h * 16 + n];
    bxpi = xv * proj[(size_t)(t - 1) * 560 + 160 + h * 16 + n];
  }

  float Ar = 1.f, Ai = 0.f, hr = 0.f, hi = 0.f;
  for (int l = 0; l < 64; ++l, ++t) {
    const float* pr = proj + (size_t)t * 560;
    const float dv  = delta[(size_t)t * 1024 + c];
    const float xv  = xc[(size_t)t * 1024 + c];
    const float brv = pr[32 + h * 16 + n];
    const float biv = pr[160 + h * 16 + n];
    const float lgr = pr[544 + h];
    const float egr = pr[552 + h];
    SCAN_STEP()
    const float nAr = are * Ar - aim * Ai;
    const float nAi = are * Ai + aim * Ar;
    Ar = nAr; Ai = nAi;
  }
  csum[gid] = make_float4(Ar, Ai, hr, hi);
}

__global__ __launch_bounds__(256)
void scan_part2_k(const float4* __restrict__ csum, float2* __restrict__ hstart) {
  const int gid = blockIdx.x * 256 + threadIdx.x;  // 32768 total
  const int low = gid & 2047;                      // d*16+n
  const int h   = (gid >> 11) & 7;
  const int b   = gid >> 14;
  float hr = 0.f, hi = 0.f;
#pragma unroll
  for (int ck = 0; ck < 16; ++ck) {
    const int s = (((b * 16 + ck) * 8 + h) << 11) + low;
    hstart[s] = make_float2(hr, hi);
    const float4 cs = csum[s];
    const float nhr = cs.x * hr - cs.y * hi + cs.z;
    const float nhi = cs.x * hi + cs.y * hr + cs.w;
    hr = nhr; hi = nhi;
  }
}

__global__ __launch_bounds__(256)
void scan_part3_k(const float* __restrict__ xz, const float* __restrict__ xc,
                  const float* __restrict__ proj, const float* __restrict__ delta,
                  const float* __restrict__ A_log, const float* __restrict__ A_imag,
                  const float* __restrict__ D_param,
                  const float2* __restrict__ hstart, float* __restrict__ ygated) {
  const int gid = blockIdx.x * 256 + threadIdx.x;
  const int n  = gid & 15;
  const int d  = (gid >> 4) & 127;
  const int h  = (gid >> 11) & 7;
  const int ck = (gid >> 14) & 15;
  const int b  = gid >> 18;
  const int c  = h * 128 + d;

  const float Are = -__expf(A_log[h * 16 + n]);
  const float Aim = A_imag[h * 16 + n];
  const float Dc  = D_param[c];

  int t = b * 1024 + ck * 64;
  float bxpr = 0.f, bxpi = 0.f;
  if (ck > 0) {
    const float xv = xc[(size_t)(t - 1) * 1024 + c];
    bxpr = xv * proj[(size_t)(t - 1) * 560 + 32 + h * 16 + n];
    bxpi = xv * proj[(size_t)(t - 1) * 560 + 160 + h * 16 + n];
  }
  const float2 h0 = hstart[gid];
  float hr = h0.x, hi = h0.y;

  for (int l = 0; l < 64; ++l, ++t) {
    const float* pr = proj + (size_t)t * 560;
    const float dv  = delta[(size_t)t * 1024 + c];
    const float xv  = xc[(size_t)t * 1024 + c];
    const float brv = pr[32 + h * 16 + n];
    const float biv = pr[160 + h * 16 + n];
    const float crv = pr[288 + h * 16 + n];
    const float civ = pr[416 + h * 16 + n];
    const float lgr = pr[544 + h];
    const float egr = pr[552 + h];
    const float zv  = xz[(size_t)t * 2048 + 1024 + c];
    SCAN_STEP()

    float y = hr * crv + hi * civ;
    y += __shfl_xor(y, 1);
    y += __shfl_xor(y, 2);
    y += __shfl_xor(y, 4);
    y += __shfl_xor(y, 8);

    if (n == 0) {
      const float yd = y + Dc * xv;
      const float g = zv / (1.f + __expf(-zv));
      ygated[(size_t)t * 1024 + c] = yd * g;
    }
  }
}

// ---------------------------------------------------------------------------
extern "C" void kernel_launch(void* const* d_in, const int* in_sizes, int n_in,
                              void* d_out, int out_size, void* d_ws, size_t ws_size,
                              hipStream_t stream) {
  (void)in_sizes; (void)n_in; (void)out_size; (void)ws_size;
  const float* x       = (const float*)d_in[0];
  const float* W_in    = (const float*)d_in[1];
  const float* conv_w  = (const float*)d_in[2];
  const float* conv_b  = (const float*)d_in[3];
  const float* W_x     = (const float*)d_in[4];
  const float* W_dt    = (const float*)d_in[5];
  const float* b_dt    = (const float*)d_in[6];
  const float* A_log   = (const float*)d_in[7];
  const float* A_imag  = (const float*)d_in[8];
  const float* D_param = (const float*)d_in[9];
  const float* W_out   = (const float*)d_in[10];
  float* out = (float*)d_out;

  // workspace layout (floats):
  float* ws     = (float*)d_ws;
  float* xz     = ws;                           // 2048 x 2048   = 4,194,304
  float* xc     = xz + (size_t)2048 * 2048;     // 2048 x 1024   = 2,097,152
  float* proj   = xc + (size_t)2048 * 1024;     // 2048 x 560    = 1,146,880
  float* delta  = proj + (size_t)2048 * 560;    // 2048 x 1024   = 2,097,152
  float* ygated = delta + (size_t)2048 * 1024;  // 2048 x 1024   = 2,097,152
  float4* csum  = (float4*)(ygated + (size_t)2048 * 1024);  // 524,288 f4
  float2* hst   = (float2*)((float*)csum + (size_t)4 * 524288);  // 524,288 f2
  // total = 14,778,368 floats = 59.1 MB

  // 1) xz = x @ W_in^T        (M=2048, N=2048, K=512)
  gemm_nt_k<<<dim3(32, 32), dim3(256), 0, stream>>>(x, W_in, xz, 2048, 512);
  // 2) xc = silu(dwconv(x_proj))
  conv_silu_k<<<dim3(8192), dim3(256), 0, stream>>>(xz, conv_w, conv_b, xc);
  // 3) proj = xc @ W_x^T      (M=2048, N=560, K=1024)
  gemm_nt_k<<<dim3(9, 32), dim3(256), 0, stream>>>(xc, W_x, proj, 560, 1024);
  // 4) delta = softplus(proj[:, :32] @ W_dt^T + b_dt)
  delta_k<<<dim3(8192), dim3(256), 0, stream>>>(proj, W_dt, b_dt, delta);
  // 5) chunked scan
  scan_part1_k<<<dim3(2048), dim3(256), 0, stream>>>(xc, proj, delta, A_log,
                                                     A_imag, csum);
  scan_part2_k<<<dim3(128), dim3(256), 0, stream>>>(csum, hst);
  scan_part3_k<<<dim3(2048), dim3(256), 0, stream>>>(xz, xc, proj, delta, A_log,
                                                     A_imag, D_param, hst, ygated);
  // 6) out = ygated @ W_out^T (M=2048, N=512, K=1024)
  gemm_nt_k<<<dim3(8, 32), dim3(256), 0, stream>>>(ygated, W_out, out, 512, 1024);
}

// Round 3
// 348.761 us; speedup vs baseline: 2.3054x; 1.2011x over previous
//
#include <hip/hip_runtime.h>
#include <hip/hip_bf16.h>
#include <math.h>

// Problem constants (B=2, L=1024, d_model=512, d_inner=1024, H=8, N=16, hd=128,
// dt_rank=32, out_dim=560). T = B*L = 2048 tokens.
//
// Pipeline:
//  1) gemm_nt: xz[T,2048]   = x[T,512]    @ W_in[2048,512]^T
//  2) conv_silu: xc[T,1024] = silu(causal_dwconv(xz[:, :1024]))
//  3) gemm_nt: proj[T,560]  = xc[T,1024]  @ W_x[560,1024]^T
//  4) pack_k : scanin[t,h,n]={Br,Bi,Cr,Ci}, gates[t,h]={1-lg, lg*eg}
//     delta_k: delta[T,1024]= softplus(proj[:, :32] @ W_dt^T + b_dt)
//  5) chunked complex scan (chunk=64, 16 chunks/seq):
//       part1: per-chunk cumulative alpha-product + zero-init end state
//       part2: 16-step scan over chunk summaries -> per-chunk carry-in
//       part3: re-run chunk from carry-in, y + D*xc, * silu(z) -> ygated
//  6) gemm_nt: out[T,512]   = ygated[T,1024] @ W_out[512,1024]^T
//
// Scan step (re-associated, trans ops in hw domains):
//   mag = exp2(max(dv*Are2, -20*log2e)),  (sn,co) = sincos_rev(dv*AimRev)
//   are = mag*co, aim = mag*sn
//   tr  = hr + betas*bxpr, ti = hi + betas*bxpi        (betas = dv*(1-lg))
//   hr' = are*tr - aim*ti + gam*bxr                    (gam   = dv*lg*eg)
//   hi' = are*ti + aim*tr + gam*bxi

__device__ __forceinline__ float fexp2(float x) {
  float r; asm("v_exp_f32 %0, %1" : "=v"(r) : "v"(x)); return r;
}
__device__ __forceinline__ float fsin_rev(float x) {
  float r; asm("v_sin_f32 %0, %1" : "=v"(r) : "v"(x)); return r;
}
__device__ __forceinline__ float fcos_rev(float x) {
  float r; asm("v_cos_f32 %0, %1" : "=v"(r) : "v"(x)); return r;
}

// ---------------------------------------------------------------------------
// Generic f32 GEMM: C[M,N] = A[M,K] * W[N,K]^T  (both row-major).
// ---------------------------------------------------------------------------
__global__ __launch_bounds__(256)
void gemm_nt_k(const float* __restrict__ A, const float* __restrict__ W,
               float* __restrict__ C, int N, int K) {
  __shared__ __align__(16) float As[16][68];
  __shared__ __align__(16) float Ws[16][68];
  const int tid  = threadIdx.x;
  const int m0   = blockIdx.y * 64;
  const int n0   = blockIdx.x * 64;
  const int tx   = tid & 15;
  const int ty   = tid >> 4;
  const int lrow = tid >> 2;
  const int lcol = (tid & 3) << 2;

  float acc[4][4] = {{0.f, 0.f, 0.f, 0.f}, {0.f, 0.f, 0.f, 0.f},
                     {0.f, 0.f, 0.f, 0.f}, {0.f, 0.f, 0.f, 0.f}};

  for (int k0 = 0; k0 < K; k0 += 16) {
    const float4 a4 =
        *reinterpret_cast<const float4*>(&A[(size_t)(m0 + lrow) * K + k0 + lcol]);
    float4 w4 = make_float4(0.f, 0.f, 0.f, 0.f);
    const int wrow = n0 + lrow;
    if (wrow < N)
      w4 = *reinterpret_cast<const float4*>(&W[(size_t)wrow * K + k0 + lcol]);

    __syncthreads();
    As[lcol + 0][lrow] = a4.x; As[lcol + 1][lrow] = a4.y;
    As[lcol + 2][lrow] = a4.z; As[lcol + 3][lrow] = a4.w;
    Ws[lcol + 0][lrow] = w4.x; Ws[lcol + 1][lrow] = w4.y;
    Ws[lcol + 2][lrow] = w4.z; Ws[lcol + 3][lrow] = w4.w;
    __syncthreads();

#pragma unroll
    for (int k = 0; k < 16; ++k) {
      const float4 av = *reinterpret_cast<const float4*>(&As[k][ty << 2]);
      const float4 wv = *reinterpret_cast<const float4*>(&Ws[k][tx << 2]);
      acc[0][0] += av.x * wv.x; acc[0][1] += av.x * wv.y;
      acc[0][2] += av.x * wv.z; acc[0][3] += av.x * wv.w;
      acc[1][0] += av.y * wv.x; acc[1][1] += av.y * wv.y;
      acc[1][2] += av.y * wv.z; acc[1][3] += av.y * wv.w;
      acc[2][0] += av.z * wv.x; acc[2][1] += av.z * wv.y;
      acc[2][2] += av.z * wv.z; acc[2][3] += av.z * wv.w;
      acc[3][0] += av.w * wv.x; acc[3][1] += av.w * wv.y;
      acc[3][2] += av.w * wv.z; acc[3][3] += av.w * wv.w;
    }
  }

#pragma unroll
  for (int i = 0; i < 4; ++i) {
    const int m = m0 + (ty << 2) + i;
#pragma unroll
    for (int j = 0; j < 4; ++j) {
      const int nn = n0 + (tx << 2) + j;
      if (nn < N) C[(size_t)m * N + nn] = acc[i][j];
    }
  }
}

// ---------------------------------------------------------------------------
// Causal depthwise conv (K=3) + silu.
// ---------------------------------------------------------------------------
__global__ __launch_bounds__(256)
void conv_silu_k(const float* __restrict__ xz, const float* __restrict__ conv_w,
                 const float* __restrict__ conv_b, float* __restrict__ xc) {
  const int idx = blockIdx.x * 256 + threadIdx.x;
  const int c = idx & 1023;
  const int t = idx >> 10;
  const int l = t & 1023;
  const float* xp = xz + (size_t)t * 2048 + c;
  float acc = conv_b[c];
  const float w0 = conv_w[c * 3 + 0];
  const float w1 = conv_w[c * 3 + 1];
  const float w2 = conv_w[c * 3 + 2];
  acc += w2 * xp[0];
  if (l >= 1) acc += w1 * xp[-2048];
  if (l >= 2) acc += w0 * xp[-2 * 2048];
  xc[idx] = acc / (1.f + __expf(-acc));
}

// ---------------------------------------------------------------------------
// delta[t,c] = softplus( proj[t,0:32] . W_dt[c,0:32] + b_dt[c] )
// ---------------------------------------------------------------------------
__global__ __launch_bounds__(256)
void delta_k(const float* __restrict__ proj, const float* __restrict__ W_dt,
             const float* __restrict__ b_dt, float* __restrict__ delta) {
  const int idx = blockIdx.x * 256 + threadIdx.x;
  const int c = idx & 1023;
  const int t = idx >> 10;
  const float* pr = proj + (size_t)t * 560;
  const float* w = W_dt + c * 32;
  float acc = b_dt[c];
#pragma unroll
  for (int r = 0; r < 32; ++r) acc += pr[r] * w[r];
  delta[idx] = fmaxf(acc, 0.f) + log1pf(__expf(-fabsf(acc)));
}

// ---------------------------------------------------------------------------
// pack: scanin[t*128+h*16+n] = {Br,Bi,Cr,Ci}; gates[t*8+h] = {1-lg, lg*eg}
// ---------------------------------------------------------------------------
__global__ __launch_bounds__(256)
void pack_k(const float* __restrict__ proj, float4* __restrict__ scanin,
            float2* __restrict__ gates) {
  const int idx = blockIdx.x * 256 + threadIdx.x;  // 262144 total
  const int n = idx & 15;
  const int h = (idx >> 4) & 7;
  const int t = idx >> 7;
  const float* pr = proj + (size_t)t * 560;
  const int hn = h * 16 + n;
  scanin[idx] = make_float4(pr[32 + hn], pr[160 + hn], pr[288 + hn], pr[416 + hn]);
  if (n == 0) {
    const float lg = 1.f / (1.f + __expf(-pr[544 + h]));
    const float eg = 1.f / (1.f + __expf(-pr[552 + h]));
    gates[t * 8 + h] = make_float2(1.f - lg, lg * eg);
  }
}

// ---------------------------------------------------------------------------
// Chunked scan.  gid bits: [b:1][chunk:4][h:3][d:7][n:4] -> 524288 threads.
// ---------------------------------------------------------------------------
#define LOG2E_20 28.853901f

__global__ __launch_bounds__(256)
void scan_part1_k(const float* __restrict__ xc, const float4* __restrict__ scanin,
                  const float* __restrict__ delta, const float2* __restrict__ gates,
                  const float* __restrict__ A_log, const float* __restrict__ A_imag,
                  float4* __restrict__ csum) {
  const int gid = blockIdx.x * 256 + threadIdx.x;
  const int n  = gid & 15;
  const int d  = (gid >> 4) & 127;
  const int h  = (gid >> 11) & 7;
  const int ck = (gid >> 14) & 15;
  const int b  = gid >> 18;
  const int c  = h * 128 + d;

  const float Are2 = -__expf(A_log[h * 16 + n]) * 1.44269504f;  // *log2(e)
  const float AimR = A_imag[h * 16 + n] * 0.15915494f;          // /(2*pi)

  int t = b * 1024 + ck * 64;
  float bxpr = 0.f, bxpi = 0.f;
  if (ck > 0) {
    const float xv = xc[(size_t)(t - 1) * 1024 + c];
    const float2 bp =
        reinterpret_cast<const float2*>(scanin)[2 * ((size_t)(t - 1) * 128 + h * 16 + n)];
    bxpr = xv * bp.x; bxpi = xv * bp.y;
  }

  const float*  dp = delta + (size_t)t * 1024 + c;
  const float*  xp = xc + (size_t)t * 1024 + c;
  const float2* sp = reinterpret_cast<const float2*>(scanin) +
                     2 * ((size_t)t * 128 + h * 16 + n);
  const float2* gp = gates + (size_t)t * 8 + h;

  float Ar = 1.f, Ai = 0.f, hr = 0.f, hi = 0.f;
  for (int l = 0; l < 64; ++l) {
    const float dv = *dp;
    const float xv = *xp;
    const float2 bc = *sp;
    const float2 bg = *gp;
    const float betas = dv * bg.x;
    const float gam   = dv * bg.y;
    const float mag = fexp2(fmaxf(dv * Are2, -LOG2E_20));
    const float rev = dv * AimR;
    const float sn = fsin_rev(rev), co = fcos_rev(rev);
    const float are = mag * co, aim = mag * sn;
    const float bxr = xv * bc.x, bxi = xv * bc.y;
    const float tr = fmaf(betas, bxpr, hr);
    const float ti = fmaf(betas, bxpi, hi);
    hr = fmaf(are, tr, fmaf(-aim, ti, gam * bxr));
    hi = fmaf(are, ti, fmaf(aim, tr, gam * bxi));
    bxpr = bxr; bxpi = bxi;
    const float nAr = fmaf(are, Ar, -aim * Ai);
    const float nAi = fmaf(are, Ai, aim * Ar);
    Ar = nAr; Ai = nAi;
    dp += 1024; xp += 1024; sp += 256; gp += 8;
  }
  csum[gid] = make_float4(Ar, Ai, hr, hi);
}

__global__ __launch_bounds__(256)
void scan_part2_k(const float4* __restrict__ csum, float2* __restrict__ hstart) {
  const int gid = blockIdx.x * 256 + threadIdx.x;  // 32768 total
  const int low = gid & 2047;
  const int h   = (gid >> 11) & 7;
  const int b   = gid >> 14;
  float hr = 0.f, hi = 0.f;
#pragma unroll
  for (int ck = 0; ck < 16; ++ck) {
    const int s = (((b * 16 + ck) * 8 + h) << 11) + low;
    hstart[s] = make_float2(hr, hi);
    const float4 cs = csum[s];
    const float nhr = cs.x * hr - cs.y * hi + cs.z;
    const float nhi = cs.x * hi + cs.y * hr + cs.w;
    hr = nhr; hi = nhi;
  }
}

__global__ __launch_bounds__(256)
void scan_part3_k(const float* __restrict__ xz, const float* __restrict__ xc,
                  const float4* __restrict__ scanin, const float* __restrict__ delta,
                  const float2* __restrict__ gates, const float* __restrict__ A_log,
                  const float* __restrict__ A_imag, const float* __restrict__ D_param,
                  const float2* __restrict__ hstart, float* __restrict__ ygated) {
  const int gid = blockIdx.x * 256 + threadIdx.x;
  const int n  = gid & 15;
  const int d  = (gid >> 4) & 127;
  const int h  = (gid >> 11) & 7;
  const int ck = (gid >> 14) & 15;
  const int b  = gid >> 18;
  const int c  = h * 128 + d;

  const float Are2 = -__expf(A_log[h * 16 + n]) * 1.44269504f;
  const float AimR = A_imag[h * 16 + n] * 0.15915494f;
  const float Dc   = D_param[c];

  int t = b * 1024 + ck * 64;
  float bxpr = 0.f, bxpi = 0.f;
  if (ck > 0) {
    const float xv = xc[(size_t)(t - 1) * 1024 + c];
    const float2 bp =
        reinterpret_cast<const float2*>(scanin)[2 * ((size_t)(t - 1) * 128 + h * 16 + n)];
    bxpr = xv * bp.x; bxpi = xv * bp.y;
  }
  const float2 h0 = hstart[gid];
  float hr = h0.x, hi = h0.y;

  const float*  dp = delta + (size_t)t * 1024 + c;
  const float*  xp = xc + (size_t)t * 1024 + c;
  const float4* sp = scanin + (size_t)t * 128 + h * 16 + n;
  const float2* gp = gates + (size_t)t * 8 + h;
  const float*  zp = xz + (size_t)t * 2048 + 1024 + c;
  float*        yp = ygated + (size_t)t * 1024 + c;

  for (int l = 0; l < 64; ++l) {
    const float dv = *dp;
    const float xv = *xp;
    const float4 bc = *sp;
    const float2 bg = *gp;
    const float betas = dv * bg.x;
    const float gam   = dv * bg.y;
    const float mag = fexp2(fmaxf(dv * Are2, -LOG2E_20));
    const float rev = dv * AimR;
    const float sn = fsin_rev(rev), co = fcos_rev(rev);
    const float are = mag * co, aim = mag * sn;
    const float bxr = xv * bc.x, bxi = xv * bc.y;
    const float tr = fmaf(betas, bxpr, hr);
    const float ti = fmaf(betas, bxpi, hi);
    hr = fmaf(are, tr, fmaf(-aim, ti, gam * bxr));
    hi = fmaf(are, ti, fmaf(aim, tr, gam * bxi));
    bxpr = bxr; bxpi = bxi;

    float y = fmaf(hr, bc.z, hi * bc.w);
    y += __shfl_xor(y, 1);
    y += __shfl_xor(y, 2);
    y += __shfl_xor(y, 4);
    y += __shfl_xor(y, 8);

    if (n == 0) {
      const float zv = *zp;
      const float yd = fmaf(Dc, xv, y);
      const float g = zv / (1.f + __expf(-zv));
      *yp = yd * g;
    }
    dp += 1024; xp += 1024; sp += 128; gp += 8; zp += 2048; yp += 1024;
  }
}

// ---------------------------------------------------------------------------
extern "C" void kernel_launch(void* const* d_in, const int* in_sizes, int n_in,
                              void* d_out, int out_size, void* d_ws, size_t ws_size,
                              hipStream_t stream) {
  (void)in_sizes; (void)n_in; (void)out_size; (void)ws_size;
  const float* x       = (const float*)d_in[0];
  const float* W_in    = (const float*)d_in[1];
  const float* conv_w  = (const float*)d_in[2];
  const float* conv_b  = (const float*)d_in[3];
  const float* W_x     = (const float*)d_in[4];
  const float* W_dt    = (const float*)d_in[5];
  const float* b_dt    = (const float*)d_in[6];
  const float* A_log   = (const float*)d_in[7];
  const float* A_imag  = (const float*)d_in[8];
  const float* D_param = (const float*)d_in[9];
  const float* W_out   = (const float*)d_in[10];
  float* out = (float*)d_out;

  // workspace layout (floats):
  float* ws     = (float*)d_ws;
  float* xz     = ws;                           // 4,194,304
  float* xc     = xz + (size_t)2048 * 2048;     // 2,097,152
  float* proj   = xc + (size_t)2048 * 1024;     // 1,146,880
  float* delta  = proj + (size_t)2048 * 560;    // 2,097,152
  float* ygated = delta + (size_t)2048 * 1024;  // 2,097,152
  float4* csum  = (float4*)(ygated + (size_t)2048 * 1024);       // 2,097,152
  float2* hst   = (float2*)((float*)csum + (size_t)4 * 524288);  // 1,048,576
  float4* scanin = (float4*)((float*)hst + (size_t)2 * 524288);  // 1,048,576
  float2* gates  = (float2*)((float*)scanin + (size_t)4 * 262144);  // 32,768
  // total = 15,859,712 floats = 63.4 MB

  // 1) xz = x @ W_in^T        (M=2048, N=2048, K=512)
  gemm_nt_k<<<dim3(32, 32), dim3(256), 0, stream>>>(x, W_in, xz, 2048, 512);
  // 2) xc = silu(dwconv(x_proj))
  conv_silu_k<<<dim3(8192), dim3(256), 0, stream>>>(xz, conv_w, conv_b, xc);
  // 3) proj = xc @ W_x^T      (M=2048, N=560, K=1024)
  gemm_nt_k<<<dim3(9, 32), dim3(256), 0, stream>>>(xc, W_x, proj, 560, 1024);
  // 4) pack + delta
  pack_k<<<dim3(1024), dim3(256), 0, stream>>>(proj, scanin, gates);
  delta_k<<<dim3(8192), dim3(256), 0, stream>>>(proj, W_dt, b_dt, delta);
  // 5) chunked scan
  scan_part1_k<<<dim3(2048), dim3(256), 0, stream>>>(xc, scanin, delta, gates,
                                                     A_log, A_imag, csum);
  scan_part2_k<<<dim3(128), dim3(256), 0, stream>>>(csum, hst);
  scan_part3_k<<<dim3(2048), dim3(256), 0, stream>>>(xz, xc, scanin, delta, gates,
                                                     A_log, A_imag, D_param, hst,
                                                     ygated);
  // 6) out = ygated @ W_out^T (M=2048, N=512, K=1024)
  gemm_nt_k<<<dim3(8, 32), dim3(256), 0, stream>>>(ygated, W_out, out, 512, 1024);
}

// Round 4
// 239.333 us; speedup vs baseline: 3.3594x; 1.4572x over previous
//
#include <hip/hip_runtime.h>
#include <hip/hip_bf16.h>
#include <math.h>

// Problem constants (B=2, L=1024, d_model=512, d_inner=1024, H=8, N=16, hd=128,
// dt_rank=32, out_dim=560). T = B*L = 2048 tokens.
//
// Pipeline (GEMMs in bf16 MFMA, everything else f32):
//  0) cvt: x,W_in,W_x,W_out -> bf16
//  1) gemm_bf16: xz[T,2048] = x_bf @ Win_bf^T          (f32 out)
//  2) conv_silu: xc = silu(dwconv(xz[:,:1024])), also writes xc_bf
//  3) gemm_bf16: proj[T,560] = xc_bf @ Wx_bf^T
//  4) pack_k / delta_k  (f32)
//  5) chunked complex scan (part1/part2/part3); part3 writes yg_bf (bf16)
//  6) gemm_bf16: out[T,512] = yg_bf @ Wout_bf^T

typedef __attribute__((ext_vector_type(8))) short bf16x8;
typedef __attribute__((ext_vector_type(4))) float f32x4;

__device__ __forceinline__ float fexp2(float x) {
  float r; asm("v_exp_f32 %0, %1" : "=v"(r) : "v"(x)); return r;
}
__device__ __forceinline__ float fsin_rev(float x) {
  float r; asm("v_sin_f32 %0, %1" : "=v"(r) : "v"(x)); return r;
}
__device__ __forceinline__ float fcos_rev(float x) {
  float r; asm("v_cos_f32 %0, %1" : "=v"(r) : "v"(x)); return r;
}
__device__ __forceinline__ short f2bf(float f) {  // round-to-nearest-even
  unsigned u = __float_as_uint(f);
  return (short)((u + 0x7FFFu + ((u >> 16) & 1u)) >> 16);
}

// ---------------------------------------------------------------------------
// f32 -> bf16 conversion, 4 elems/thread.
// ---------------------------------------------------------------------------
__global__ __launch_bounds__(256)
void cvt_bf16_k(const float* __restrict__ src, short* __restrict__ dst, int n4) {
  const int i = blockIdx.x * 256 + threadIdx.x;
  if (i < n4) {
    const float4 v = reinterpret_cast<const float4*>(src)[i];
    short4 o;
    o.x = f2bf(v.x); o.y = f2bf(v.y); o.z = f2bf(v.z); o.w = f2bf(v.w);
    reinterpret_cast<short4*>(dst)[i] = o;
  }
}

// ---------------------------------------------------------------------------
// bf16 MFMA GEMM (NT): C[M,N] f32 = A[M,K]bf16 * W[N,K]bf16^T.
// 128x128 tile / 256 threads (4 waves, each a 64x64 quadrant of 4x4 16x16
// frags), BK=32, reg-staged LDS with +8-short pad (stride 80B: banks 20r%32,
// 2-way max -> free per m136).  M multiple of 128; N guarded.
// ---------------------------------------------------------------------------
__global__ __launch_bounds__(256)
void gemm_bf16_k(const short* __restrict__ A, const short* __restrict__ W,
                 float* __restrict__ C, int N, int K) {
  __shared__ short As[128][40];
  __shared__ short Ws[128][40];
  const int tid  = threadIdx.x;
  const int m0   = blockIdx.y * 128;
  const int n0   = blockIdx.x * 128;
  const int lane = tid & 63;
  const int wid  = tid >> 6;
  const int wm   = (wid >> 1) * 64;
  const int wn   = (wid & 1) * 64;
  const int r0   = tid >> 2;        // 0..63: staging row
  const int q    = (tid & 3) * 8;   // staging k-offset (elements)
  const int lrow = lane & 15;
  const int lk   = (lane >> 4) * 8;

  f32x4 acc[4][4] = {};

  for (int k0 = 0; k0 < K; k0 += 32) {
    const size_t abase = (size_t)(m0 + r0) * K + k0 + q;
    const uint4 a0v = *reinterpret_cast<const uint4*>(A + abase);
    const uint4 a1v = *reinterpret_cast<const uint4*>(A + abase + (size_t)64 * K);
    const int wr0 = n0 + r0, wr1 = wr0 + 64;
    uint4 w0v = make_uint4(0, 0, 0, 0), w1v = make_uint4(0, 0, 0, 0);
    if (wr0 < N) w0v = *reinterpret_cast<const uint4*>(W + (size_t)wr0 * K + k0 + q);
    if (wr1 < N) w1v = *reinterpret_cast<const uint4*>(W + (size_t)wr1 * K + k0 + q);

    __syncthreads();  // previous iteration's readers done
    *reinterpret_cast<uint4*>(&As[r0][q])      = a0v;
    *reinterpret_cast<uint4*>(&As[r0 + 64][q]) = a1v;
    *reinterpret_cast<uint4*>(&Ws[r0][q])      = w0v;
    *reinterpret_cast<uint4*>(&Ws[r0 + 64][q]) = w1v;
    __syncthreads();

    bf16x8 af[4], bfr[4];
#pragma unroll
    for (int i = 0; i < 4; ++i)
      af[i] = *reinterpret_cast<const bf16x8*>(&As[wm + i * 16 + lrow][lk]);
#pragma unroll
    for (int j = 0; j < 4; ++j)
      bfr[j] = *reinterpret_cast<const bf16x8*>(&Ws[wn + j * 16 + lrow][lk]);
#pragma unroll
    for (int i = 0; i < 4; ++i)
#pragma unroll
      for (int j = 0; j < 4; ++j)
        acc[i][j] = __builtin_amdgcn_mfma_f32_16x16x32_bf16(af[i], bfr[j],
                                                            acc[i][j], 0, 0, 0);
  }

  // epilogue: C/D layout col=lane&15, row=(lane>>4)*4+reg (m89)
  const int crow = (lane >> 4) * 4;
  const int ccol = lane & 15;
#pragma unroll
  for (int i = 0; i < 4; ++i) {
#pragma unroll
    for (int j = 0; j < 4; ++j) {
      const int col = n0 + wn + j * 16 + ccol;
      if (col < N) {
        const int row = m0 + wm + i * 16 + crow;
#pragma unroll
        for (int r = 0; r < 4; ++r)
          C[(size_t)(row + r) * N + col] = acc[i][j][r];
      }
    }
  }
}

// ---------------------------------------------------------------------------
// Causal depthwise conv (K=3) + silu; writes f32 and bf16 copies.
// ---------------------------------------------------------------------------
__global__ __launch_bounds__(256)
void conv_silu_k(const float* __restrict__ xz, const float* __restrict__ conv_w,
                 const float* __restrict__ conv_b, float* __restrict__ xc,
                 short* __restrict__ xcb) {
  const int idx = blockIdx.x * 256 + threadIdx.x;
  const int c = idx & 1023;
  const int t = idx >> 10;
  const int l = t & 1023;
  const float* xp = xz + (size_t)t * 2048 + c;
  float acc = conv_b[c];
  const float w0 = conv_w[c * 3 + 0];
  const float w1 = conv_w[c * 3 + 1];
  const float w2 = conv_w[c * 3 + 2];
  acc += w2 * xp[0];
  if (l >= 1) acc += w1 * xp[-2048];
  if (l >= 2) acc += w0 * xp[-2 * 2048];
  const float v = acc / (1.f + __expf(-acc));
  xc[idx] = v;
  xcb[idx] = f2bf(v);
}

// ---------------------------------------------------------------------------
// delta[t,c] = softplus( proj[t,0:32] . W_dt[c,0:32] + b_dt[c] )
// ---------------------------------------------------------------------------
__global__ __launch_bounds__(256)
void delta_k(const float* __restrict__ proj, const float* __restrict__ W_dt,
             const float* __restrict__ b_dt, float* __restrict__ delta) {
  const int idx = blockIdx.x * 256 + threadIdx.x;
  const int c = idx & 1023;
  const int t = idx >> 10;
  const float* pr = proj + (size_t)t * 560;
  const float* w = W_dt + c * 32;
  float acc = b_dt[c];
#pragma unroll
  for (int r = 0; r < 32; ++r) acc += pr[r] * w[r];
  delta[idx] = fmaxf(acc, 0.f) + log1pf(__expf(-fabsf(acc)));
}

// ---------------------------------------------------------------------------
// pack: scanin[t*128+h*16+n] = {Br,Bi,Cr,Ci}; gates[t*8+h] = {1-lg, lg*eg}
// ---------------------------------------------------------------------------
__global__ __launch_bounds__(256)
void pack_k(const float* __restrict__ proj, float4* __restrict__ scanin,
            float2* __restrict__ gates) {
  const int idx = blockIdx.x * 256 + threadIdx.x;  // 262144 total
  const int n = idx & 15;
  const int h = (idx >> 4) & 7;
  const int t = idx >> 7;
  const float* pr = proj + (size_t)t * 560;
  const int hn = h * 16 + n;
  scanin[idx] = make_float4(pr[32 + hn], pr[160 + hn], pr[288 + hn], pr[416 + hn]);
  if (n == 0) {
    const float lg = 1.f / (1.f + __expf(-pr[544 + h]));
    const float eg = 1.f / (1.f + __expf(-pr[552 + h]));
    gates[t * 8 + h] = make_float2(1.f - lg, lg * eg);
  }
}

// ---------------------------------------------------------------------------
// Chunked scan.  gid bits: [b:1][chunk:4][h:3][d:7][n:4] -> 524288 threads.
// ---------------------------------------------------------------------------
#define LOG2E_20 28.853901f

__global__ __launch_bounds__(256)
void scan_part1_k(const float* __restrict__ xc, const float4* __restrict__ scanin,
                  const float* __restrict__ delta, const float2* __restrict__ gates,
                  const float* __restrict__ A_log, const float* __restrict__ A_imag,
                  float4* __restrict__ csum) {
  const int gid = blockIdx.x * 256 + threadIdx.x;
  const int n  = gid & 15;
  const int d  = (gid >> 4) & 127;
  const int h  = (gid >> 11) & 7;
  const int ck = (gid >> 14) & 15;
  const int b  = gid >> 18;
  const int c  = h * 128 + d;

  const float Are2 = -__expf(A_log[h * 16 + n]) * 1.44269504f;  // *log2(e)
  const float AimR = A_imag[h * 16 + n] * 0.15915494f;          // /(2*pi)

  int t = b * 1024 + ck * 64;
  float bxpr = 0.f, bxpi = 0.f;
  if (ck > 0) {
    const float xv = xc[(size_t)(t - 1) * 1024 + c];
    const float2 bp =
        reinterpret_cast<const float2*>(scanin)[2 * ((size_t)(t - 1) * 128 + h * 16 + n)];
    bxpr = xv * bp.x; bxpi = xv * bp.y;
  }

  const float*  dp = delta + (size_t)t * 1024 + c;
  const float*  xp = xc + (size_t)t * 1024 + c;
  const float2* sp = reinterpret_cast<const float2*>(scanin) +
                     2 * ((size_t)t * 128 + h * 16 + n);
  const float2* gp = gates + (size_t)t * 8 + h;

  float Ar = 1.f, Ai = 0.f, hr = 0.f, hi = 0.f;
  for (int l = 0; l < 64; ++l) {
    const float dv = *dp;
    const float xv = *xp;
    const float2 bc = *sp;
    const float2 bg = *gp;
    const float betas = dv * bg.x;
    const float gam   = dv * bg.y;
    const float mag = fexp2(fmaxf(dv * Are2, -LOG2E_20));
    const float rev = dv * AimR;
    const float sn = fsin_rev(rev), co = fcos_rev(rev);
    const float are = mag * co, aim = mag * sn;
    const float bxr = xv * bc.x, bxi = xv * bc.y;
    const float tr = fmaf(betas, bxpr, hr);
    const float ti = fmaf(betas, bxpi, hi);
    hr = fmaf(are, tr, fmaf(-aim, ti, gam * bxr));
    hi = fmaf(are, ti, fmaf(aim, tr, gam * bxi));
    bxpr = bxr; bxpi = bxi;
    const float nAr = fmaf(are, Ar, -aim * Ai);
    const float nAi = fmaf(are, Ai, aim * Ar);
    Ar = nAr; Ai = nAi;
    dp += 1024; xp += 1024; sp += 256; gp += 8;
  }
  csum[gid] = make_float4(Ar, Ai, hr, hi);
}

__global__ __launch_bounds__(256)
void scan_part2_k(const float4* __restrict__ csum, float2* __restrict__ hstart) {
  const int gid = blockIdx.x * 256 + threadIdx.x;  // 32768 total
  const int low = gid & 2047;
  const int h   = (gid >> 11) & 7;
  const int b   = gid >> 14;
  float hr = 0.f, hi = 0.f;
#pragma unroll
  for (int ck = 0; ck < 16; ++ck) {
    const int s = (((b * 16 + ck) * 8 + h) << 11) + low;
    hstart[s] = make_float2(hr, hi);
    const float4 cs = csum[s];
    const float nhr = cs.x * hr - cs.y * hi + cs.z;
    const float nhi = cs.x * hi + cs.y * hr + cs.w;
    hr = nhr; hi = nhi;
  }
}

__global__ __launch_bounds__(256)
void scan_part3_k(const float* __restrict__ xz, const float* __restrict__ xc,
                  const float4* __restrict__ scanin, const float* __restrict__ delta,
                  const float2* __restrict__ gates, const float* __restrict__ A_log,
                  const float* __restrict__ A_imag, const float* __restrict__ D_param,
                  const float2* __restrict__ hstart, short* __restrict__ ygb) {
  const int gid = blockIdx.x * 256 + threadIdx.x;
  const int n  = gid & 15;
  const int d  = (gid >> 4) & 127;
  const int h  = (gid >> 11) & 7;
  const int ck = (gid >> 14) & 15;
  const int b  = gid >> 18;
  const int c  = h * 128 + d;

  const float Are2 = -__expf(A_log[h * 16 + n]) * 1.44269504f;
  const float AimR = A_imag[h * 16 + n] * 0.15915494f;
  const float Dc   = D_param[c];

  int t = b * 1024 + ck * 64;
  float bxpr = 0.f, bxpi = 0.f;
  if (ck > 0) {
    const float xv = xc[(size_t)(t - 1) * 1024 + c];
    const float2 bp =
        reinterpret_cast<const float2*>(scanin)[2 * ((size_t)(t - 1) * 128 + h * 16 + n)];
    bxpr = xv * bp.x; bxpi = xv * bp.y;
  }
  const float2 h0 = hstart[gid];
  float hr = h0.x, hi = h0.y;

  const float*  dp = delta + (size_t)t * 1024 + c;
  const float*  xp = xc + (size_t)t * 1024 + c;
  const float4* sp = scanin + (size_t)t * 128 + h * 16 + n;
  const float2* gp = gates + (size_t)t * 8 + h;
  const float*  zp = xz + (size_t)t * 2048 + 1024 + c;
  short*        yp = ygb + (size_t)t * 1024 + c;

  for (int l = 0; l < 64; ++l) {
    const float dv = *dp;
    const float xv = *xp;
    const float4 bc = *sp;
    const float2 bg = *gp;
    const float betas = dv * bg.x;
    const float gam   = dv * bg.y;
    const float mag = fexp2(fmaxf(dv * Are2, -LOG2E_20));
    const float rev = dv * AimR;
    const float sn = fsin_rev(rev), co = fcos_rev(rev);
    const float are = mag * co, aim = mag * sn;
    const float bxr = xv * bc.x, bxi = xv * bc.y;
    const float tr = fmaf(betas, bxpr, hr);
    const float ti = fmaf(betas, bxpi, hi);
    hr = fmaf(are, tr, fmaf(-aim, ti, gam * bxr));
    hi = fmaf(are, ti, fmaf(aim, tr, gam * bxi));
    bxpr = bxr; bxpi = bxi;

    float y = fmaf(hr, bc.z, hi * bc.w);
    y += __shfl_xor(y, 1);
    y += __shfl_xor(y, 2);
    y += __shfl_xor(y, 4);
    y += __shfl_xor(y, 8);

    if (n == 0) {
      const float zv = *zp;
      const float yd = fmaf(Dc, xv, y);
      const float g = zv / (1.f + __expf(-zv));
      *yp = f2bf(yd * g);
    }
    dp += 1024; xp += 1024; sp += 128; gp += 8; zp += 2048; yp += 1024;
  }
}

// ---------------------------------------------------------------------------
extern "C" void kernel_launch(void* const* d_in, const int* in_sizes, int n_in,
                              void* d_out, int out_size, void* d_ws, size_t ws_size,
                              hipStream_t stream) {
  (void)in_sizes; (void)n_in; (void)out_size; (void)ws_size;
  const float* x       = (const float*)d_in[0];
  const float* W_in    = (const float*)d_in[1];
  const float* conv_w  = (const float*)d_in[2];
  const float* conv_b  = (const float*)d_in[3];
  const float* W_x     = (const float*)d_in[4];
  const float* W_dt    = (const float*)d_in[5];
  const float* b_dt    = (const float*)d_in[6];
  const float* A_log   = (const float*)d_in[7];
  const float* A_imag  = (const float*)d_in[8];
  const float* D_param = (const float*)d_in[9];
  const float* W_out   = (const float*)d_in[10];
  float* out = (float*)d_out;

  // workspace layout (float offsets); total 16,121,856 floats = 61.5 MiB.
  // Aliases (disjoint lifetimes): x_bf+Win_bf live inside csum's slot (dead
  // before part1 writes csum); Wx_bf lives inside hst's slot (dead before
  // part2 writes hst).
  float* ws = (float*)d_ws;
  float*  xz     = ws;                               // 4,194,304
  float*  xc     = ws + 4194304;                     // 2,097,152
  float*  proj   = ws + 6291456;                     // 1,146,880
  float*  delta  = ws + 7438336;                     // 2,097,152
  float4* scanin = (float4*)(ws + 9535488);          // 1,048,576
  float2* gates  = (float2*)(ws + 10584064);         //    32,768
  short*  xc_bf  = (short*)(ws + 10616832);          // 1,048,576 (2M shorts)
  short*  yg_bf  = (short*)(ws + 11665408);          // 1,048,576
  short*  wout_bf= (short*)(ws + 12713984);          //   262,144
  float4* csum   = (float4*)(ws + 12976128);         // 2,097,152
  short*  x_bf   = (short*)(ws + 12976128);          //   [alias in csum]
  short*  win_bf = (short*)(ws + 13500416);          //   [alias in csum]
  float2* hst    = (float2*)(ws + 15073280);         // 1,048,576
  short*  wx_bf  = (short*)(ws + 15073280);          //   [alias in hst]

  // 0) conversions to bf16
  cvt_bf16_k<<<dim3(1024), dim3(256), 0, stream>>>(x, x_bf, 262144);
  cvt_bf16_k<<<dim3(1024), dim3(256), 0, stream>>>(W_in, win_bf, 262144);
  cvt_bf16_k<<<dim3(560), dim3(256), 0, stream>>>(W_x, wx_bf, 143360);
  cvt_bf16_k<<<dim3(512), dim3(256), 0, stream>>>(W_out, wout_bf, 131072);
  // 1) xz = x @ W_in^T        (M=2048, N=2048, K=512)
  gemm_bf16_k<<<dim3(16, 16), dim3(256), 0, stream>>>(x_bf, win_bf, xz, 2048, 512);
  // 2) xc = silu(dwconv(x_proj)) (+ bf16 copy)
  conv_silu_k<<<dim3(8192), dim3(256), 0, stream>>>(xz, conv_w, conv_b, xc, xc_bf);
  // 3) proj = xc @ W_x^T      (M=2048, N=560, K=1024)
  gemm_bf16_k<<<dim3(5, 16), dim3(256), 0, stream>>>(xc_bf, wx_bf, proj, 560, 1024);
  // 4) pack + delta
  pack_k<<<dim3(1024), dim3(256), 0, stream>>>(proj, scanin, gates);
  delta_k<<<dim3(8192), dim3(256), 0, stream>>>(proj, W_dt, b_dt, delta);
  // 5) chunked scan
  scan_part1_k<<<dim3(2048), dim3(256), 0, stream>>>(xc, scanin, delta, gates,
                                                     A_log, A_imag, csum);
  scan_part2_k<<<dim3(128), dim3(256), 0, stream>>>(csum, hst);
  scan_part3_k<<<dim3(2048), dim3(256), 0, stream>>>(xz, xc, scanin, delta, gates,
                                                     A_log, A_imag, D_param, hst,
                                                     yg_bf);
  // 6) out = yg_bf @ W_out^T  (M=2048, N=512, K=1024)
  gemm_bf16_k<<<dim3(4, 16), dim3(256), 0, stream>>>(yg_bf, wout_bf, out, 512, 1024);
}

// Round 5
// 207.527 us; speedup vs baseline: 3.8743x; 1.1533x over previous
//
#include <hip/hip_runtime.h>
#include <hip/hip_bf16.h>
#include <math.h>

// Problem constants (B=2, L=1024, d_model=512, d_inner=1024, H=8, N=16, hd=128,
// dt_rank=32, out_dim=560). T = B*L = 2048 tokens.
//
// Pipeline (GEMMs in bf16 MFMA, scan math f32):
//  0) cvt_all: x,W_in,W_x,W_out -> bf16 (one kernel); wdtT: W_dt transpose
//  1) gemm_bf16_128: xz[T,2048] = x_bf @ Win_bf^T        (f32 out)
//  2) conv_silu: dx[t,c].y = silu(dwconv(xz[:,:1024])), xc_bf (bf16 copy)
//  3) gemm_bf16_64: proj[T,560] = xc_bf @ Wx_bf^T
//  4) pack2: dx[t,c].x = softplus(proj[:, :32] . W_dtT + b_dt);
//            scanin[t,h,n]={Br,Bi,Cr,Ci}; gates[t,h]={1-lg, lg*eg}
//  5) chunked complex scan (part1/part2/part3); part3 writes yg_bf (bf16)
//  6) gemm_bf16_64: out[T,512] = yg_bf @ Wout_bf^T

typedef __attribute__((ext_vector_type(8))) short bf16x8;
typedef __attribute__((ext_vector_type(4))) float f32x4;

__device__ __forceinline__ float fexp2(float x) {
  float r; asm("v_exp_f32 %0, %1" : "=v"(r) : "v"(x)); return r;
}
__device__ __forceinline__ float fsin_rev(float x) {
  float r; asm("v_sin_f32 %0, %1" : "=v"(r) : "v"(x)); return r;
}
__device__ __forceinline__ float fcos_rev(float x) {
  float r; asm("v_cos_f32 %0, %1" : "=v"(r) : "v"(x)); return r;
}
__device__ __forceinline__ short f2bf(float f) {  // round-to-nearest-even
  unsigned u = __float_as_uint(f);
  return (short)((u + 0x7FFFu + ((u >> 16) & 1u)) >> 16);
}

// ---------------------------------------------------------------------------
// Fused f32->bf16 conversion of x, W_in, W_x, W_out (float4 granules).
// Segment sizes: 262144 | 262144 | 143360 | 131072  (total 798720).
// ---------------------------------------------------------------------------
__global__ __launch_bounds__(256)
void cvt_all_k(const float* __restrict__ x, const float* __restrict__ W_in,
               const float* __restrict__ W_x, const float* __restrict__ W_out,
               short* __restrict__ x_bf, short* __restrict__ win_bf,
               short* __restrict__ wx_bf, short* __restrict__ wout_bf) {
  const int i = blockIdx.x * 256 + threadIdx.x;
  const float4* src; short4* dst; int off;
  if (i < 262144)      { src = (const float4*)x;     dst = (short4*)x_bf;    off = i; }
  else if (i < 524288) { src = (const float4*)W_in;  dst = (short4*)win_bf;  off = i - 262144; }
  else if (i < 667648) { src = (const float4*)W_x;   dst = (short4*)wx_bf;   off = i - 524288; }
  else                 { src = (const float4*)W_out; dst = (short4*)wout_bf; off = i - 667648; }
  const float4 v = src[off];
  short4 o;
  o.x = f2bf(v.x); o.y = f2bf(v.y); o.z = f2bf(v.z); o.w = f2bf(v.w);
  dst[off] = o;
}

// W_dtT[r*1024+c] = W_dt[c*32+r]   (coalesced write)
__global__ __launch_bounds__(256)
void wdtT_k(const float* __restrict__ W_dt, float* __restrict__ W_dtT) {
  const int i = blockIdx.x * 256 + threadIdx.x;  // 32768
  const int c = i & 1023, r = i >> 10;
  W_dtT[i] = W_dt[c * 32 + r];
}

// ---------------------------------------------------------------------------
// bf16 MFMA GEMM (NT), 128x128 tile / 256 threads (4 waves x 64x64 quadrant).
// BK=32, LDS +8-short pad (row stride 80 B -> 2-way bank alias, free).
// ---------------------------------------------------------------------------
__global__ __launch_bounds__(256)
void gemm_bf16_128(const short* __restrict__ A, const short* __restrict__ W,
                   float* __restrict__ C, int N, int K) {
  __shared__ short As[128][40];
  __shared__ short Ws[128][40];
  const int tid  = threadIdx.x;
  const int m0   = blockIdx.y * 128;
  const int n0   = blockIdx.x * 128;
  const int lane = tid & 63;
  const int wid  = tid >> 6;
  const int wm   = (wid >> 1) * 64;
  const int wn   = (wid & 1) * 64;
  const int r0   = tid >> 2;
  const int q    = (tid & 3) * 8;
  const int lrow = lane & 15;
  const int lk   = (lane >> 4) * 8;

  f32x4 acc[4][4] = {};

  for (int k0 = 0; k0 < K; k0 += 32) {
    const size_t abase = (size_t)(m0 + r0) * K + k0 + q;
    const uint4 a0v = *reinterpret_cast<const uint4*>(A + abase);
    const uint4 a1v = *reinterpret_cast<const uint4*>(A + abase + (size_t)64 * K);
    const int wr0 = n0 + r0, wr1 = wr0 + 64;
    uint4 w0v = make_uint4(0, 0, 0, 0), w1v = make_uint4(0, 0, 0, 0);
    if (wr0 < N) w0v = *reinterpret_cast<const uint4*>(W + (size_t)wr0 * K + k0 + q);
    if (wr1 < N) w1v = *reinterpret_cast<const uint4*>(W + (size_t)wr1 * K + k0 + q);

    __syncthreads();
    *reinterpret_cast<uint4*>(&As[r0][q])      = a0v;
    *reinterpret_cast<uint4*>(&As[r0 + 64][q]) = a1v;
    *reinterpret_cast<uint4*>(&Ws[r0][q])      = w0v;
    *reinterpret_cast<uint4*>(&Ws[r0 + 64][q]) = w1v;
    __syncthreads();

    bf16x8 af[4], bfr[4];
#pragma unroll
    for (int i = 0; i < 4; ++i)
      af[i] = *reinterpret_cast<const bf16x8*>(&As[wm + i * 16 + lrow][lk]);
#pragma unroll
    for (int j = 0; j < 4; ++j)
      bfr[j] = *reinterpret_cast<const bf16x8*>(&Ws[wn + j * 16 + lrow][lk]);
#pragma unroll
    for (int i = 0; i < 4; ++i)
#pragma unroll
      for (int j = 0; j < 4; ++j)
        acc[i][j] = __builtin_amdgcn_mfma_f32_16x16x32_bf16(af[i], bfr[j],
                                                            acc[i][j], 0, 0, 0);
  }

  const int crow = (lane >> 4) * 4;
  const int ccol = lane & 15;
#pragma unroll
  for (int i = 0; i < 4; ++i) {
#pragma unroll
    for (int j = 0; j < 4; ++j) {
      const int col = n0 + wn + j * 16 + ccol;
      if (col < N) {
        const int row = m0 + wm + i * 16 + crow;
#pragma unroll
        for (int r = 0; r < 4; ++r)
          C[(size_t)(row + r) * N + col] = acc[i][j][r];
      }
    }
  }
}

// ---------------------------------------------------------------------------
// bf16 MFMA GEMM (NT), 64x64 tile / 256 threads (4 waves x 32x32 quadrant).
// For small-N GEMMs (more blocks -> better CU coverage).
// ---------------------------------------------------------------------------
__global__ __launch_bounds__(256)
void gemm_bf16_64(const short* __restrict__ A, const short* __restrict__ W,
                  float* __restrict__ C, int N, int K) {
  __shared__ short As[64][40];
  __shared__ short Ws[64][40];
  const int tid  = threadIdx.x;
  const int m0   = blockIdx.y * 64;
  const int n0   = blockIdx.x * 64;
  const int lane = tid & 63;
  const int wid  = tid >> 6;
  const int wm   = (wid >> 1) * 32;
  const int wn   = (wid & 1) * 32;
  const int r0   = tid >> 2;
  const int q    = (tid & 3) * 8;
  const int lrow = lane & 15;
  const int lk   = (lane >> 4) * 8;

  f32x4 acc[2][2] = {};

  for (int k0 = 0; k0 < K; k0 += 32) {
    const uint4 a0v =
        *reinterpret_cast<const uint4*>(A + (size_t)(m0 + r0) * K + k0 + q);
    const int wr0 = n0 + r0;
    uint4 w0v = make_uint4(0, 0, 0, 0);
    if (wr0 < N) w0v = *reinterpret_cast<const uint4*>(W + (size_t)wr0 * K + k0 + q);

    __syncthreads();
    *reinterpret_cast<uint4*>(&As[r0][q]) = a0v;
    *reinterpret_cast<uint4*>(&Ws[r0][q]) = w0v;
    __syncthreads();

    bf16x8 af[2], bfr[2];
#pragma unroll
    for (int i = 0; i < 2; ++i)
      af[i] = *reinterpret_cast<const bf16x8*>(&As[wm + i * 16 + lrow][lk]);
#pragma unroll
    for (int j = 0; j < 2; ++j)
      bfr[j] = *reinterpret_cast<const bf16x8*>(&Ws[wn + j * 16 + lrow][lk]);
#pragma unroll
    for (int i = 0; i < 2; ++i)
#pragma unroll
      for (int j = 0; j < 2; ++j)
        acc[i][j] = __builtin_amdgcn_mfma_f32_16x16x32_bf16(af[i], bfr[j],
                                                            acc[i][j], 0, 0, 0);
  }

  const int crow = (lane >> 4) * 4;
  const int ccol = lane & 15;
#pragma unroll
  for (int i = 0; i < 2; ++i) {
#pragma unroll
    for (int j = 0; j < 2; ++j) {
      const int col = n0 + wn + j * 16 + ccol;
      if (col < N) {
        const int row = m0 + wm + i * 16 + crow;
#pragma unroll
        for (int r = 0; r < 4; ++r)
          C[(size_t)(row + r) * N + col] = acc[i][j][r];
      }
    }
  }
}

// ---------------------------------------------------------------------------
// Causal depthwise conv (K=3) + silu; writes dx.y (f32) and xc_bf (bf16).
// ---------------------------------------------------------------------------
__global__ __launch_bounds__(256)
void conv_silu_k(const float* __restrict__ xz, const float* __restrict__ conv_w,
                 const float* __restrict__ conv_b, float* __restrict__ dxf,
                 short* __restrict__ xcb) {
  const int idx = blockIdx.x * 256 + threadIdx.x;
  const int c = idx & 1023;
  const int t = idx >> 10;
  const int l = t & 1023;
  const float* xp = xz + (size_t)t * 2048 + c;
  float acc = conv_b[c];
  const float w0 = conv_w[c * 3 + 0];
  const float w1 = conv_w[c * 3 + 1];
  const float w2 = conv_w[c * 3 + 2];
  acc += w2 * xp[0];
  if (l >= 1) acc += w1 * xp[-2048];
  if (l >= 2) acc += w0 * xp[-2 * 2048];
  const float v = acc / (1.f + __expf(-acc));
  dxf[2 * (size_t)idx + 1] = v;
  xcb[idx] = f2bf(v);
}

// ---------------------------------------------------------------------------
// pack2: fused delta + scanin-pack + gates.
//  idx <  2M : dx[t,c].x = softplus(proj[t,0:32] . W_dtT[:,c] + b_dt[c])
//  idx >= 2M : scanin[t,h,n] = {Br,Bi,Cr,Ci};  n==0: gates[t,h]
// ---------------------------------------------------------------------------
__global__ __launch_bounds__(256)
void pack2_k(const float* __restrict__ proj, const float* __restrict__ W_dtT,
             const float* __restrict__ b_dt, float* __restrict__ dxf,
             float4* __restrict__ scanin, float2* __restrict__ gates) {
  const int idx = blockIdx.x * 256 + threadIdx.x;  // 2097152 + 262144
  if (idx < 2097152) {
    const int c = idx & 1023;
    const int t = idx >> 10;
    const float* pr = proj + (size_t)t * 560;
    float acc = b_dt[c];
#pragma unroll
    for (int r = 0; r < 32; ++r) acc = fmaf(pr[r], W_dtT[r * 1024 + c], acc);
    dxf[2 * (size_t)idx] = fmaxf(acc, 0.f) + log1pf(__expf(-fabsf(acc)));
  } else {
    const int j = idx - 2097152;
    const int n = j & 15;
    const int h = (j >> 4) & 7;
    const int t = j >> 7;
    const float* pr = proj + (size_t)t * 560;
    const int hn = h * 16 + n;
    scanin[j] = make_float4(pr[32 + hn], pr[160 + hn], pr[288 + hn], pr[416 + hn]);
    if (n == 0) {
      const float lg = 1.f / (1.f + __expf(-pr[544 + h]));
      const float eg = 1.f / (1.f + __expf(-pr[552 + h]));
      gates[t * 8 + h] = make_float2(1.f - lg, lg * eg);
    }
  }
}

// ---------------------------------------------------------------------------
// Chunked scan.  gid bits: [b:1][chunk:4][h:3][d:7][n:4] -> 524288 threads.
// Step: mag=exp2(dv*Are2) (no clip: dv*Are2<=0, diff vs ref <= e-20);
//       (sn,co)=sincos_rev(dv*AimR); tr=h+betas*bxp; h'=a*tr + gam*bx.
// ---------------------------------------------------------------------------
__global__ __launch_bounds__(256)
void scan_part1_k(const float2* __restrict__ dx, const float4* __restrict__ scanin,
                  const float2* __restrict__ gates, const float* __restrict__ A_log,
                  const float* __restrict__ A_imag, float4* __restrict__ csum) {
  const int gid = blockIdx.x * 256 + threadIdx.x;
  const int n  = gid & 15;
  const int d  = (gid >> 4) & 127;
  const int h  = (gid >> 11) & 7;
  const int ck = (gid >> 14) & 15;
  const int b  = gid >> 18;
  const int c  = h * 128 + d;

  const float Are2 = -__expf(A_log[h * 16 + n]) * 1.44269504f;  // *log2(e)
  const float AimR = A_imag[h * 16 + n] * 0.15915494f;          // /(2*pi)

  const int t0 = b * 1024 + ck * 64;
  float bxpr = 0.f, bxpi = 0.f;
  if (ck > 0) {
    const float xv = dx[(size_t)(t0 - 1) * 1024 + c].y;
    const float2 bp =
        reinterpret_cast<const float2*>(scanin)[2 * ((size_t)(t0 - 1) * 128 + h * 16 + n)];
    bxpr = xv * bp.x; bxpi = xv * bp.y;
  }

  const float2* dxp = dx + (size_t)t0 * 1024 + c;
  const float2* sp  = reinterpret_cast<const float2*>(scanin) +
                      2 * ((size_t)t0 * 128 + h * 16 + n);
  const float2* gp  = gates + (size_t)t0 * 8 + h;

  float Ar = 1.f, Ai = 0.f, hr = 0.f, hi = 0.f;
#pragma unroll 2
  for (int l = 0; l < 64; ++l) {
    const float2 dxv = *dxp;
    const float2 bc = *sp;
    const float2 bg = *gp;
    const float dv = dxv.x, xv = dxv.y;
    const float betas = dv * bg.x;
    const float gam   = dv * bg.y;
    const float mag = fexp2(dv * Are2);
    const float rev = dv * AimR;
    const float sn = fsin_rev(rev), co = fcos_rev(rev);
    const float are = mag * co, aim = mag * sn;
    const float bxr = xv * bc.x, bxi = xv * bc.y;
    const float tr = fmaf(betas, bxpr, hr);
    const float ti = fmaf(betas, bxpi, hi);
    hr = fmaf(are, tr, fmaf(-aim, ti, gam * bxr));
    hi = fmaf(are, ti, fmaf(aim, tr, gam * bxi));
    bxpr = bxr; bxpi = bxi;
    const float nAr = fmaf(are, Ar, -aim * Ai);
    const float nAi = fmaf(are, Ai, aim * Ar);
    Ar = nAr; Ai = nAi;
    dxp += 1024; sp += 256; gp += 8;
  }
  csum[gid] = make_float4(Ar, Ai, hr, hi);
}

__global__ __launch_bounds__(256)
void scan_part2_k(const float4* __restrict__ csum, float2* __restrict__ hstart) {
  const int gid = blockIdx.x * 256 + threadIdx.x;  // 32768 total
  const int low = gid & 2047;
  const int h   = (gid >> 11) & 7;
  const int b   = gid >> 14;
  float hr = 0.f, hi = 0.f;
#pragma unroll
  for (int ck = 0; ck < 16; ++ck) {
    const int s = (((b * 16 + ck) * 8 + h) << 11) + low;
    hstart[s] = make_float2(hr, hi);
    const float4 cs = csum[s];
    const float nhr = cs.x * hr - cs.y * hi + cs.z;
    const float nhi = cs.x * hi + cs.y * hr + cs.w;
    hr = nhr; hi = nhi;
  }
}

__global__ __launch_bounds__(256)
void scan_part3_k(const float* __restrict__ xz, const float2* __restrict__ dx,
                  const float4* __restrict__ scanin, const float2* __restrict__ gates,
                  const float* __restrict__ A_log, const float* __restrict__ A_imag,
                  const float* __restrict__ D_param,
                  const float2* __restrict__ hstart, short* __restrict__ ygb) {
  const int gid = blockIdx.x * 256 + threadIdx.x;
  const int n  = gid & 15;
  const int d  = (gid >> 4) & 127;
  const int h  = (gid >> 11) & 7;
  const int ck = (gid >> 14) & 15;
  const int b  = gid >> 18;
  const int c  = h * 128 + d;

  const float Are2 = -__expf(A_log[h * 16 + n]) * 1.44269504f;
  const float AimR = A_imag[h * 16 + n] * 0.15915494f;
  const float Dc   = D_param[c];

  const int t0 = b * 1024 + ck * 64;
  float bxpr = 0.f, bxpi = 0.f;
  if (ck > 0) {
    const float xv = dx[(size_t)(t0 - 1) * 1024 + c].y;
    const float2 bp =
        reinterpret_cast<const float2*>(scanin)[2 * ((size_t)(t0 - 1) * 128 + h * 16 + n)];
    bxpr = xv * bp.x; bxpi = xv * bp.y;
  }
  const float2 h0 = hstart[gid];
  float hr = h0.x, hi = h0.y;

  const float2* dxp = dx + (size_t)t0 * 1024 + c;
  const float4* sp  = scanin + (size_t)t0 * 128 + h * 16 + n;
  const float2* gp  = gates + (size_t)t0 * 8 + h;
  const float*  zp  = xz + (size_t)t0 * 2048 + 1024 + c;
  short*        yp  = ygb + (size_t)t0 * 1024 + c;

#pragma unroll 2
  for (int l = 0; l < 64; ++l) {
    const float2 dxv = *dxp;
    const float4 bc = *sp;
    const float2 bg = *gp;
    const float dv = dxv.x, xv = dxv.y;
    const float betas = dv * bg.x;
    const float gam   = dv * bg.y;
    const float mag = fexp2(dv * Are2);
    const float rev = dv * AimR;
    const float sn = fsin_rev(rev), co = fcos_rev(rev);
    const float are = mag * co, aim = mag * sn;
    const float bxr = xv * bc.x, bxi = xv * bc.y;
    const float tr = fmaf(betas, bxpr, hr);
    const float ti = fmaf(betas, bxpi, hi);
    hr = fmaf(are, tr, fmaf(-aim, ti, gam * bxr));
    hi = fmaf(are, ti, fmaf(aim, tr, gam * bxi));
    bxpr = bxr; bxpi = bxi;

    float y = fmaf(hr, bc.z, hi * bc.w);
    y += __shfl_xor(y, 1);
    y += __shfl_xor(y, 2);
    y += __shfl_xor(y, 4);
    y += __shfl_xor(y, 8);

    if (n == 0) {
      const float zv = *zp;
      const float yd = fmaf(Dc, xv, y);
      const float g = zv / (1.f + __expf(-zv));
      *yp = f2bf(yd * g);
    }
    dxp += 1024; sp += 128; gp += 8; zp += 2048; yp += 1024;
  }
}

// ---------------------------------------------------------------------------
extern "C" void kernel_launch(void* const* d_in, const int* in_sizes, int n_in,
                              void* d_out, int out_size, void* d_ws, size_t ws_size,
                              hipStream_t stream) {
  (void)in_sizes; (void)n_in; (void)out_size; (void)ws_size;
  const float* x       = (const float*)d_in[0];
  const float* W_in    = (const float*)d_in[1];
  const float* conv_w  = (const float*)d_in[2];
  const float* conv_b  = (const float*)d_in[3];
  const float* W_x     = (const float*)d_in[4];
  const float* W_dt    = (const float*)d_in[5];
  const float* b_dt    = (const float*)d_in[6];
  const float* A_log   = (const float*)d_in[7];
  const float* A_imag  = (const float*)d_in[8];
  const float* D_param = (const float*)d_in[9];
  const float* W_out   = (const float*)d_in[10];
  float* out = (float*)d_out;

  // workspace layout (float offsets); total 15,106,048 floats = 57.6 MiB.
  // Aliases (disjoint lifetimes): x_bf/win_bf/xc_bf live inside csum's slot
  // (all dead before part1 writes csum); wx_bf/wdtT inside hst's slot (dead
  // before part2 writes hst).  wout_bf is standalone (used by last GEMM).
  float* ws = (float*)d_ws;
  float*  xz      = ws;                          // 4,194,304
  float*  proj    = ws + 4194304;                // 1,146,880
  float2* dx      = (float2*)(ws + 5341184);     // 4,194,304 (2M float2)
  float4* scanin  = (float4*)(ws + 9535488);     // 1,048,576
  float2* gates   = (float2*)(ws + 10584064);    //    65,536
  short*  yg_bf   = (short*)(ws + 10649600);     // 1,048,576 (2M shorts)
  short*  wout_bf = (short*)(ws + 11698176);     //   262,144
  float4* csum    = (float4*)(ws + 11960320);    // 2,097,152
  short*  x_bf    = (short*)(ws + 11960320);     //   [alias in csum]
  short*  win_bf  = (short*)(ws + 12484608);     //   [alias in csum]
  short*  xc_bf   = (short*)(ws + 13008896);     //   [alias in csum]
  float2* hst     = (float2*)(ws + 14057472);    // 1,048,576
  short*  wx_bf   = (short*)(ws + 14057472);     //   [alias in hst]
  float*  wdtT    = ws + 14344192;               //   [alias in hst]

  // 0) conversions + W_dt transpose
  cvt_all_k<<<dim3(3120), dim3(256), 0, stream>>>(x, W_in, W_x, W_out, x_bf,
                                                  win_bf, wx_bf, wout_bf);
  wdtT_k<<<dim3(128), dim3(256), 0, stream>>>(W_dt, wdtT);
  // 1) xz = x @ W_in^T        (M=2048, N=2048, K=512)
  gemm_bf16_128<<<dim3(16, 16), dim3(256), 0, stream>>>(x_bf, win_bf, xz, 2048, 512);
  // 2) dx.y = silu(dwconv(x_proj)) (+ bf16 copy)
  conv_silu_k<<<dim3(8192), dim3(256), 0, stream>>>(xz, conv_w, conv_b,
                                                    (float*)dx, xc_bf);
  // 3) proj = xc @ W_x^T      (M=2048, N=560, K=1024)
  gemm_bf16_64<<<dim3(9, 32), dim3(256), 0, stream>>>(xc_bf, wx_bf, proj, 560, 1024);
  // 4) dx.x = delta; scanin/gates pack
  pack2_k<<<dim3(9216), dim3(256), 0, stream>>>(proj, wdtT, b_dt, (float*)dx,
                                                scanin, gates);
  // 5) chunked scan
  scan_part1_k<<<dim3(2048), dim3(256), 0, stream>>>(dx, scanin, gates, A_log,
                                                     A_imag, csum);
  scan_part2_k<<<dim3(128), dim3(256), 0, stream>>>(csum, hst);
  scan_part3_k<<<dim3(2048), dim3(256), 0, stream>>>(xz, dx, scanin, gates, A_log,
                                                     A_imag, D_param, hst, yg_bf);
  // 6) out = yg_bf @ W_out^T  (M=2048, N=512, K=1024)
  gemm_bf16_64<<<dim3(8, 32), dim3(256), 0, stream>>>(yg_bf, wout_bf, out, 512, 1024);
}

// Round 6
// 203.713 us; speedup vs baseline: 3.9468x; 1.0187x over previous
//
#include <hip/hip_runtime.h>
#include <hip/hip_bf16.h>
#include <math.h>

// Problem constants (B=2, L=1024, d_model=512, d_inner=1024, H=8, N=16, hd=128,
// dt_rank=32, out_dim=560). T = B*L = 2048 tokens.
//
// Pipeline (GEMMs in bf16 MFMA, scan math f32):
//  0) cvt_all: x,W_in,W_x,W_out -> bf16 + W_dt transpose (one kernel)
//  1) gemm_bf16_128: xz[T,2048] = x_bf @ Win_bf^T        (f32 out)
//  2) conv_silu: dx[t,c].y = silu(dwconv(xz[:,:1024])), xc_bf (bf16 copy)
//  3) gemm_bf16_64: proj[T,560] = xc_bf @ Wx_bf^T
//  4) pack2: dx[t,c].x = softplus(proj[:, :32] . W_dtT + b_dt);
//            scanin[t,h,n]={Br,Bi,Cr,Ci}; gates[t,h]={1-lg, lg*eg}
//  5) chunked complex scan (part1/part2/part3); part3 writes yg_bf (bf16)
//     part1/part3 loops are software-pipelined (1-step register prefetch).
//  6) gemm_bf16_64: out[T,512] = yg_bf @ Wout_bf^T

typedef __attribute__((ext_vector_type(8))) short bf16x8;
typedef __attribute__((ext_vector_type(4))) float f32x4;

__device__ __forceinline__ float fexp2(float x) {
  float r; asm("v_exp_f32 %0, %1" : "=v"(r) : "v"(x)); return r;
}
__device__ __forceinline__ float fsin_rev(float x) {
  float r; asm("v_sin_f32 %0, %1" : "=v"(r) : "v"(x)); return r;
}
__device__ __forceinline__ float fcos_rev(float x) {
  float r; asm("v_cos_f32 %0, %1" : "=v"(r) : "v"(x)); return r;
}
__device__ __forceinline__ short f2bf(float f) {  // round-to-nearest-even
  unsigned u = __float_as_uint(f);
  return (short)((u + 0x7FFFu + ((u >> 16) & 1u)) >> 16);
}

// ---------------------------------------------------------------------------
// Fused f32->bf16 conversion of x, W_in, W_x, W_out (float4 granules) plus
// W_dt transpose.  Segments: 262144 | 262144 | 143360 | 131072 f4 granules,
// then 32768 scalar transpose elems.  Grid 3248*256 = 831488 = exact.
// ---------------------------------------------------------------------------
__global__ __launch_bounds__(256)
void cvt_all_k(const float* __restrict__ x, const float* __restrict__ W_in,
               const float* __restrict__ W_x, const float* __restrict__ W_out,
               const float* __restrict__ W_dt,
               short* __restrict__ x_bf, short* __restrict__ win_bf,
               short* __restrict__ wx_bf, short* __restrict__ wout_bf,
               float* __restrict__ W_dtT) {
  const int i = blockIdx.x * 256 + threadIdx.x;
  if (i < 798720) {
    const float4* src; short4* dst; int off;
    if (i < 262144)      { src = (const float4*)x;     dst = (short4*)x_bf;    off = i; }
    else if (i < 524288) { src = (const float4*)W_in;  dst = (short4*)win_bf;  off = i - 262144; }
    else if (i < 667648) { src = (const float4*)W_x;   dst = (short4*)wx_bf;   off = i - 524288; }
    else                 { src = (const float4*)W_out; dst = (short4*)wout_bf; off = i - 667648; }
    const float4 v = src[off];
    short4 o;
    o.x = f2bf(v.x); o.y = f2bf(v.y); o.z = f2bf(v.z); o.w = f2bf(v.w);
    dst[off] = o;
  } else {
    const int j = i - 798720;  // 0..32767: W_dtT[r*1024+c] = W_dt[c*32+r]
    W_dtT[j] = W_dt[(j & 1023) * 32 + (j >> 10)];
  }
}

// ---------------------------------------------------------------------------
// bf16 MFMA GEMM (NT), 128x128 tile / 256 threads (4 waves x 64x64 quadrant).
// BK=32, LDS +8-short pad (row stride 80 B -> 2-way bank alias, free).
// ---------------------------------------------------------------------------
__global__ __launch_bounds__(256)
void gemm_bf16_128(const short* __restrict__ A, const short* __restrict__ W,
                   float* __restrict__ C, int N, int K) {
  __shared__ short As[128][40];
  __shared__ short Ws[128][40];
  const int tid  = threadIdx.x;
  const int m0   = blockIdx.y * 128;
  const int n0   = blockIdx.x * 128;
  const int lane = tid & 63;
  const int wid  = tid >> 6;
  const int wm   = (wid >> 1) * 64;
  const int wn   = (wid & 1) * 64;
  const int r0   = tid >> 2;
  const int q    = (tid & 3) * 8;
  const int lrow = lane & 15;
  const int lk   = (lane >> 4) * 8;

  f32x4 acc[4][4] = {};

  for (int k0 = 0; k0 < K; k0 += 32) {
    const size_t abase = (size_t)(m0 + r0) * K + k0 + q;
    const uint4 a0v = *reinterpret_cast<const uint4*>(A + abase);
    const uint4 a1v = *reinterpret_cast<const uint4*>(A + abase + (size_t)64 * K);
    const int wr0 = n0 + r0, wr1 = wr0 + 64;
    uint4 w0v = make_uint4(0, 0, 0, 0), w1v = make_uint4(0, 0, 0, 0);
    if (wr0 < N) w0v = *reinterpret_cast<const uint4*>(W + (size_t)wr0 * K + k0 + q);
    if (wr1 < N) w1v = *reinterpret_cast<const uint4*>(W + (size_t)wr1 * K + k0 + q);

    __syncthreads();
    *reinterpret_cast<uint4*>(&As[r0][q])      = a0v;
    *reinterpret_cast<uint4*>(&As[r0 + 64][q]) = a1v;
    *reinterpret_cast<uint4*>(&Ws[r0][q])      = w0v;
    *reinterpret_cast<uint4*>(&Ws[r0 + 64][q]) = w1v;
    __syncthreads();

    bf16x8 af[4], bfr[4];
#pragma unroll
    for (int i = 0; i < 4; ++i)
      af[i] = *reinterpret_cast<const bf16x8*>(&As[wm + i * 16 + lrow][lk]);
#pragma unroll
    for (int j = 0; j < 4; ++j)
      bfr[j] = *reinterpret_cast<const bf16x8*>(&Ws[wn + j * 16 + lrow][lk]);
#pragma unroll
    for (int i = 0; i < 4; ++i)
#pragma unroll
      for (int j = 0; j < 4; ++j)
        acc[i][j] = __builtin_amdgcn_mfma_f32_16x16x32_bf16(af[i], bfr[j],
                                                            acc[i][j], 0, 0, 0);
  }

  const int crow = (lane >> 4) * 4;
  const int ccol = lane & 15;
#pragma unroll
  for (int i = 0; i < 4; ++i) {
#pragma unroll
    for (int j = 0; j < 4; ++j) {
      const int col = n0 + wn + j * 16 + ccol;
      if (col < N) {
        const int row = m0 + wm + i * 16 + crow;
#pragma unroll
        for (int r = 0; r < 4; ++r)
          C[(size_t)(row + r) * N + col] = acc[i][j][r];
      }
    }
  }
}

// ---------------------------------------------------------------------------
// bf16 MFMA GEMM (NT), 64x64 tile / 256 threads (4 waves x 32x32 quadrant).
// ---------------------------------------------------------------------------
__global__ __launch_bounds__(256)
void gemm_bf16_64(const short* __restrict__ A, const short* __restrict__ W,
                  float* __restrict__ C, int N, int K) {
  __shared__ short As[64][40];
  __shared__ short Ws[64][40];
  const int tid  = threadIdx.x;
  const int m0   = blockIdx.y * 64;
  const int n0   = blockIdx.x * 64;
  const int lane = tid & 63;
  const int wid  = tid >> 6;
  const int wm   = (wid >> 1) * 32;
  const int wn   = (wid & 1) * 32;
  const int r0   = tid >> 2;
  const int q    = (tid & 3) * 8;
  const int lrow = lane & 15;
  const int lk   = (lane >> 4) * 8;

  f32x4 acc[2][2] = {};

  for (int k0 = 0; k0 < K; k0 += 32) {
    const uint4 a0v =
        *reinterpret_cast<const uint4*>(A + (size_t)(m0 + r0) * K + k0 + q);
    const int wr0 = n0 + r0;
    uint4 w0v = make_uint4(0, 0, 0, 0);
    if (wr0 < N) w0v = *reinterpret_cast<const uint4*>(W + (size_t)wr0 * K + k0 + q);

    __syncthreads();
    *reinterpret_cast<uint4*>(&As[r0][q]) = a0v;
    *reinterpret_cast<uint4*>(&Ws[r0][q]) = w0v;
    __syncthreads();

    bf16x8 af[2], bfr[2];
#pragma unroll
    for (int i = 0; i < 2; ++i)
      af[i] = *reinterpret_cast<const bf16x8*>(&As[wm + i * 16 + lrow][lk]);
#pragma unroll
    for (int j = 0; j < 2; ++j)
      bfr[j] = *reinterpret_cast<const bf16x8*>(&Ws[wn + j * 16 + lrow][lk]);
#pragma unroll
    for (int i = 0; i < 2; ++i)
#pragma unroll
      for (int j = 0; j < 2; ++j)
        acc[i][j] = __builtin_amdgcn_mfma_f32_16x16x32_bf16(af[i], bfr[j],
                                                            acc[i][j], 0, 0, 0);
  }

  const int crow = (lane >> 4) * 4;
  const int ccol = lane & 15;
#pragma unroll
  for (int i = 0; i < 2; ++i) {
#pragma unroll
    for (int j = 0; j < 2; ++j) {
      const int col = n0 + wn + j * 16 + ccol;
      if (col < N) {
        const int row = m0 + wm + i * 16 + crow;
#pragma unroll
        for (int r = 0; r < 4; ++r)
          C[(size_t)(row + r) * N + col] = acc[i][j][r];
      }
    }
  }
}

// ---------------------------------------------------------------------------
// Causal depthwise conv (K=3) + silu; writes dx.y (f32) and xc_bf (bf16).
// ---------------------------------------------------------------------------
__global__ __launch_bounds__(256)
void conv_silu_k(const float* __restrict__ xz, const float* __restrict__ conv_w,
                 const float* __restrict__ conv_b, float* __restrict__ dxf,
                 short* __restrict__ xcb) {
  const int idx = blockIdx.x * 256 + threadIdx.x;
  const int c = idx & 1023;
  const int t = idx >> 10;
  const int l = t & 1023;
  const float* xp = xz + (size_t)t * 2048 + c;
  float acc = conv_b[c];
  const float w0 = conv_w[c * 3 + 0];
  const float w1 = conv_w[c * 3 + 1];
  const float w2 = conv_w[c * 3 + 2];
  acc += w2 * xp[0];
  if (l >= 1) acc += w1 * xp[-2048];
  if (l >= 2) acc += w0 * xp[-2 * 2048];
  const float v = acc / (1.f + __expf(-acc));
  dxf[2 * (size_t)idx + 1] = v;
  xcb[idx] = f2bf(v);
}

// ---------------------------------------------------------------------------
// pack2: fused delta + scanin-pack + gates.
// ---------------------------------------------------------------------------
__global__ __launch_bounds__(256)
void pack2_k(const float* __restrict__ proj, const float* __restrict__ W_dtT,
             const float* __restrict__ b_dt, float* __restrict__ dxf,
             float4* __restrict__ scanin, float2* __restrict__ gates) {
  const int idx = blockIdx.x * 256 + threadIdx.x;  // 2097152 + 262144
  if (idx < 2097152) {
    const int c = idx & 1023;
    const int t = idx >> 10;
    const float* pr = proj + (size_t)t * 560;
    float acc = b_dt[c];
#pragma unroll
    for (int r = 0; r < 32; ++r) acc = fmaf(pr[r], W_dtT[r * 1024 + c], acc);
    dxf[2 * (size_t)idx] = fmaxf(acc, 0.f) + log1pf(__expf(-fabsf(acc)));
  } else {
    const int j = idx - 2097152;
    const int n = j & 15;
    const int h = (j >> 4) & 7;
    const int t = j >> 7;
    const float* pr = proj + (size_t)t * 560;
    const int hn = h * 16 + n;
    scanin[j] = make_float4(pr[32 + hn], pr[160 + hn], pr[288 + hn], pr[416 + hn]);
    if (n == 0) {
      const float lg = 1.f / (1.f + __expf(-pr[544 + h]));
      const float eg = 1.f / (1.f + __expf(-pr[552 + h]));
      gates[t * 8 + h] = make_float2(1.f - lg, lg * eg);
    }
  }
}

// ---------------------------------------------------------------------------
// Chunked scan.  gid bits: [b:1][chunk:4][h:3][d:7][n:4] -> 524288 threads.
// Step: mag=exp2(dv*Are2); (sn,co)=sincos_rev(dv*AimR); tr=h+betas*bxp;
//       h'=a*tr + gam*bx.   Loops are software-pipelined: next step's
//       operands are loaded at iteration top, consumed next iteration.
// Prefetch at the final step reads one row past each stream; all such
// addresses stay inside d_ws (values unused) -- see workspace layout.
// part1 alpha-cumprod uses sum(dv):  prod alpha = exp2(S*Are2)*cis(S*AimR);
// safe: mag underflows to 0 long before S*AimR reaches sincos range limit.
// ---------------------------------------------------------------------------
__global__ __launch_bounds__(256)
void scan_part1_k(const float2* __restrict__ dx, const float4* __restrict__ scanin,
                  const float2* __restrict__ gates, const float* __restrict__ A_log,
                  const float* __restrict__ A_imag, float4* __restrict__ csum) {
  const int gid = blockIdx.x * 256 + threadIdx.x;
  const int n  = gid & 15;
  const int d  = (gid >> 4) & 127;
  const int h  = (gid >> 11) & 7;
  const int ck = (gid >> 14) & 15;
  const int b  = gid >> 18;
  const int c  = h * 128 + d;

  const float Are2 = -__expf(A_log[h * 16 + n]) * 1.44269504f;  // *log2(e)
  const float AimR = A_imag[h * 16 + n] * 0.15915494f;          // /(2*pi)

  const int t0 = b * 1024 + ck * 64;
  float bxpr = 0.f, bxpi = 0.f;
  if (ck > 0) {
    const float xv = dx[(size_t)(t0 - 1) * 1024 + c].y;
    const float2 bp =
        reinterpret_cast<const float2*>(scanin)[2 * ((size_t)(t0 - 1) * 128 + h * 16 + n)];
    bxpr = xv * bp.x; bxpi = xv * bp.y;
  }

  const float2* dxp = dx + (size_t)t0 * 1024 + c;
  const float2* sp  = reinterpret_cast<const float2*>(scanin) +
                      2 * ((size_t)t0 * 128 + h * 16 + n);
  const float2* gp  = gates + (size_t)t0 * 8 + h;

  float2 dxv = *dxp;
  float2 bc  = *sp;
  float2 bg  = *gp;
  float S = 0.f, hr = 0.f, hi = 0.f;
#pragma unroll 2
  for (int l = 0; l < 64; ++l) {
    dxp += 1024; sp += 256; gp += 8;
    const float2 dxv_n = *dxp;   // prefetch next step
    const float2 bc_n  = *sp;
    const float2 bg_n  = *gp;

    const float dv = dxv.x, xv = dxv.y;
    const float betas = dv * bg.x;
    const float gam   = dv * bg.y;
    const float mag = fexp2(dv * Are2);
    const float rev = dv * AimR;
    const float sn = fsin_rev(rev), co = fcos_rev(rev);
    const float are = mag * co, aim = mag * sn;
    const float bxr = xv * bc.x, bxi = xv * bc.y;
    const float tr = fmaf(betas, bxpr, hr);
    const float ti = fmaf(betas, bxpi, hi);
    hr = fmaf(are, tr, fmaf(-aim, ti, gam * bxr));
    hi = fmaf(are, ti, fmaf(aim, tr, gam * bxi));
    bxpr = bxr; bxpi = bxi;
    S += dv;

    dxv = dxv_n; bc = bc_n; bg = bg_n;
  }
  const float Amag = fexp2(S * Are2);
  const float Arev = S * AimR;
  csum[gid] = make_float4(Amag * fcos_rev(Arev), Amag * fsin_rev(Arev), hr, hi);
}

__global__ __launch_bounds__(256)
void scan_part2_k(const float4* __restrict__ csum, float2* __restrict__ hstart) {
  const int gid = blockIdx.x * 256 + threadIdx.x;  // 32768 total
  const int low = gid & 2047;
  const int h   = (gid >> 11) & 7;
  const int b   = gid >> 14;
  float hr = 0.f, hi = 0.f;
#pragma unroll
  for (int ck = 0; ck < 16; ++ck) {
    const int s = (((b * 16 + ck) * 8 + h) << 11) + low;
    hstart[s] = make_float2(hr, hi);
    const float4 cs = csum[s];
    const float nhr = cs.x * hr - cs.y * hi + cs.z;
    const float nhi = cs.x * hi + cs.y * hr + cs.w;
    hr = nhr; hi = nhi;
  }
}

__global__ __launch_bounds__(256)
void scan_part3_k(const float* __restrict__ xz, const float2* __restrict__ dx,
                  const float4* __restrict__ scanin, const float2* __restrict__ gates,
                  const float* __restrict__ A_log, const float* __restrict__ A_imag,
                  const float* __restrict__ D_param,
                  const float2* __restrict__ hstart, short* __restrict__ ygb) {
  const int gid = blockIdx.x * 256 + threadIdx.x;
  const int n  = gid & 15;
  const int d  = (gid >> 4) & 127;
  const int h  = (gid >> 11) & 7;
  const int ck = (gid >> 14) & 15;
  const int b  = gid >> 18;
  const int c  = h * 128 + d;

  const float Are2 = -__expf(A_log[h * 16 + n]) * 1.44269504f;
  const float AimR = A_imag[h * 16 + n] * 0.15915494f;
  const float Dc   = D_param[c];

  const int t0 = b * 1024 + ck * 64;
  float bxpr = 0.f, bxpi = 0.f;
  if (ck > 0) {
    const float xv = dx[(size_t)(t0 - 1) * 1024 + c].y;
    const float2 bp =
        reinterpret_cast<const float2*>(scanin)[2 * ((size_t)(t0 - 1) * 128 + h * 16 + n)];
    bxpr = xv * bp.x; bxpi = xv * bp.y;
  }
  const float2 h0 = hstart[gid];
  float hr = h0.x, hi = h0.y;

  const float2* dxp = dx + (size_t)t0 * 1024 + c;
  const float4* sp  = scanin + (size_t)t0 * 128 + h * 16 + n;
  const float2* gp  = gates + (size_t)t0 * 8 + h;
  const float*  zp  = xz + (size_t)t0 * 2048 + 1024 + c;
  short*        yp  = ygb + (size_t)t0 * 1024 + c;

  float2 dxv = *dxp;
  float4 bc  = *sp;
  float2 bg  = *gp;
  float  zv  = *zp;
#pragma unroll 2
  for (int l = 0; l < 64; ++l) {
    dxp += 1024; sp += 128; gp += 8; zp += 2048;
    const float2 dxv_n = *dxp;   // prefetch next step
    const float4 bc_n  = *sp;
    const float2 bg_n  = *gp;
    const float  zv_n  = *zp;

    const float dv = dxv.x, xv = dxv.y;
    const float betas = dv * bg.x;
    const float gam   = dv * bg.y;
    const float mag = fexp2(dv * Are2);
    const float rev = dv * AimR;
    const float sn = fsin_rev(rev), co = fcos_rev(rev);
    const float are = mag * co, aim = mag * sn;
    const float bxr = xv * bc.x, bxi = xv * bc.y;
    const float tr = fmaf(betas, bxpr, hr);
    const float ti = fmaf(betas, bxpi, hi);
    hr = fmaf(are, tr, fmaf(-aim, ti, gam * bxr));
    hi = fmaf(are, ti, fmaf(aim, tr, gam * bxi));
    bxpr = bxr; bxpi = bxi;

    float y = fmaf(hr, bc.z, hi * bc.w);
    y += __shfl_xor(y, 1);
    y += __shfl_xor(y, 2);
    y += __shfl_xor(y, 4);
    y += __shfl_xor(y, 8);

    const float g = zv / (1.f + __expf(-zv));          // all lanes (pipelined)
    const short yo = f2bf(fmaf(Dc, xv, y) * g);
    if (n == 0) *yp = yo;                              // masked store only
    yp += 1024;

    dxv = dxv_n; bc = bc_n; bg = bg_n; zv = zv_n;
  }
}

// ---------------------------------------------------------------------------
extern "C" void kernel_launch(void* const* d_in, const int* in_sizes, int n_in,
                              void* d_out, int out_size, void* d_ws, size_t ws_size,
                              hipStream_t stream) {
  (void)in_sizes; (void)n_in; (void)out_size; (void)ws_size;
  const float* x       = (const float*)d_in[0];
  const float* W_in    = (const float*)d_in[1];
  const float* conv_w  = (const float*)d_in[2];
  const float* conv_b  = (const float*)d_in[3];
  const float* W_x     = (const float*)d_in[4];
  const float* W_dt    = (const float*)d_in[5];
  const float* b_dt    = (const float*)d_in[6];
  const float* A_log   = (const float*)d_in[7];
  const float* A_imag  = (const float*)d_in[8];
  const float* D_param = (const float*)d_in[9];
  const float* W_out   = (const float*)d_in[10];
  float* out = (float*)d_out;

  // workspace layout (float offsets); total 15,106,048 floats = 57.6 MiB.
  // Aliases (disjoint lifetimes): x_bf/win_bf/xc_bf live inside csum's slot
  // (all dead before part1 writes csum); wx_bf/wdtT inside hst's slot (dead
  // before part2 writes hst).  Scan prefetch overreads one row past dx /
  // scanin / gates / xz -- all land in subsequent ws buffers (allocated).
  float* ws = (float*)d_ws;
  float*  xz      = ws;                          // 4,194,304
  float*  proj    = ws + 4194304;                // 1,146,880
  float2* dx      = (float2*)(ws + 5341184);     // 4,194,304 (2M float2)
  float4* scanin  = (float4*)(ws + 9535488);     // 1,048,576
  float2* gates   = (float2*)(ws + 10584064);    //    65,536
  short*  yg_bf   = (short*)(ws + 10649600);     // 1,048,576 (2M shorts)
  short*  wout_bf = (short*)(ws + 11698176);     //   262,144
  float4* csum    = (float4*)(ws + 11960320);    // 2,097,152
  short*  x_bf    = (short*)(ws + 11960320);     //   [alias in csum]
  short*  win_bf  = (short*)(ws + 12484608);     //   [alias in csum]
  short*  xc_bf   = (short*)(ws + 13008896);     //   [alias in csum]
  float2* hst     = (float2*)(ws + 14057472);    // 1,048,576
  short*  wx_bf   = (short*)(ws + 14057472);     //   [alias in hst]
  float*  wdtT    = ws + 14344192;               //   [alias in hst]

  // 0) conversions + W_dt transpose (one kernel)
  cvt_all_k<<<dim3(3248), dim3(256), 0, stream>>>(x, W_in, W_x, W_out, W_dt,
                                                  x_bf, win_bf, wx_bf, wout_bf,
                                                  wdtT);
  // 1) xz = x @ W_in^T        (M=2048, N=2048, K=512)
  gemm_bf16_128<<<dim3(16, 16), dim3(256), 0, stream>>>(x_bf, win_bf, xz, 2048, 512);
  // 2) dx.y = silu(dwconv(x_proj)) (+ bf16 copy)
  conv_silu_k<<<dim3(8192), dim3(256), 0, stream>>>(xz, conv_w, conv_b,
                                                    (float*)dx, xc_bf);
  // 3) proj = xc @ W_x^T      (M=2048, N=560, K=1024)
  gemm_bf16_64<<<dim3(9, 32), dim3(256), 0, stream>>>(xc_bf, wx_bf, proj, 560, 1024);
  // 4) dx.x = delta; scanin/gates pack
  pack2_k<<<dim3(9216), dim3(256), 0, stream>>>(proj, wdtT, b_dt, (float*)dx,
                                                scanin, gates);
  // 5) chunked scan (software-pipelined)
  scan_part1_k<<<dim3(2048), dim3(256), 0, stream>>>(dx, scanin, gates, A_log,
                                                     A_imag, csum);
  scan_part2_k<<<dim3(128), dim3(256), 0, stream>>>(csum, hst);
  scan_part3_k<<<dim3(2048), dim3(256), 0, stream>>>(xz, dx, scanin, gates, A_log,
                                                     A_imag, D_param, hst, yg_bf);
  // 6) out = yg_bf @ W_out^T  (M=2048, N=512, K=1024)
  gemm_bf16_64<<<dim3(8, 32), dim3(256), 0, stream>>>(yg_bf, wout_bf, out, 512, 1024);
}

// Round 7
// 200.189 us; speedup vs baseline: 4.0163x; 1.0176x over previous
//
#include <hip/hip_runtime.h>
#include <hip/hip_bf16.h>
#include <math.h>

// Problem constants (B=2, L=1024, d_model=512, d_inner=1024, H=8, N=16, hd=128,
// dt_rank=32, out_dim=560). T = B*L = 2048 tokens.
//
// Pipeline (GEMMs in bf16 MFMA, scan math f32):
//  0) cvt_all: x,W_in,W_x,W_out -> bf16 + W_dt transpose (one kernel)
//  1) gemm_bf16_128: xz[T,2048] = x_bf @ Win_bf^T        (f32 out)
//  2) conv_silu: dx[t,c].y = silu(dwconv(xz[:,:1024])), xc_bf (bf16 copy),
//     AND in-place silu on the z-half: xz[t,1024+c] = silu(xz[t,1024+c])
//  3) gemm_bf16_64: proj[T,560] = xc_bf @ Wx_bf^T
//  4) pack2: dx[t,c].x = softplus(proj[:, :32] . W_dtT + b_dt);
//            scanin[t,h,n]={Br,Bi,Cr,Ci}; gates[t,h]={1-lg, lg*eg}
//  5) chunked complex scan (part1/part2/part3); part3 writes yg_bf (bf16)
//     part1/part3: depth-2 software pipeline (load l+2 while computing l);
//     part3 n-reduce via DPP row_ror adds (no LDS shuffles).
//  6) gemm_bf16_64: out[T,512] = yg_bf @ Wout_bf^T

typedef __attribute__((ext_vector_type(8))) short bf16x8;
typedef __attribute__((ext_vector_type(4))) float f32x4;

__device__ __forceinline__ float fexp2(float x) {
  float r; asm("v_exp_f32 %0, %1" : "=v"(r) : "v"(x)); return r;
}
__device__ __forceinline__ float fsin_rev(float x) {
  float r; asm("v_sin_f32 %0, %1" : "=v"(r) : "v"(x)); return r;
}
__device__ __forceinline__ float fcos_rev(float x) {
  float r; asm("v_cos_f32 %0, %1" : "=v"(r) : "v"(x)); return r;
}
__device__ __forceinline__ short f2bf(float f) {  // round-to-nearest-even
  unsigned u = __float_as_uint(f);
  return (short)((u + 0x7FFFu + ((u >> 16) & 1u)) >> 16);
}

// sum across the 16-lane row (n = lane&15) via DPP rotations; all lanes get
// the total.  row_ror:k = dpp_ctrl 0x120|k; rows of 16 align with n-groups.
#define ROR_ADD(y, CTRL)                                                     \
  {                                                                          \
    int _r = __builtin_amdgcn_update_dpp(0, __float_as_int(y), CTRL, 0xF,    \
                                         0xF, false);                        \
    y += __int_as_float(_r);                                                 \
  }

// ---------------------------------------------------------------------------
// Fused f32->bf16 conversion of x, W_in, W_x, W_out (float4 granules) plus
// W_dt transpose.  Segments: 262144 | 262144 | 143360 | 131072 f4 granules,
// then 32768 scalar transpose elems.  Grid 3248*256 = 831488 = exact.
// ---------------------------------------------------------------------------
__global__ __launch_bounds__(256)
void cvt_all_k(const float* __restrict__ x, const float* __restrict__ W_in,
               const float* __restrict__ W_x, const float* __restrict__ W_out,
               const float* __restrict__ W_dt,
               short* __restrict__ x_bf, short* __restrict__ win_bf,
               short* __restrict__ wx_bf, short* __restrict__ wout_bf,
               float* __restrict__ W_dtT) {
  const int i = blockIdx.x * 256 + threadIdx.x;
  if (i < 798720) {
    const float4* src; short4* dst; int off;
    if (i < 262144)      { src = (const float4*)x;     dst = (short4*)x_bf;    off = i; }
    else if (i < 524288) { src = (const float4*)W_in;  dst = (short4*)win_bf;  off = i - 262144; }
    else if (i < 667648) { src = (const float4*)W_x;   dst = (short4*)wx_bf;   off = i - 524288; }
    else                 { src = (const float4*)W_out; dst = (short4*)wout_bf; off = i - 667648; }
    const float4 v = src[off];
    short4 o;
    o.x = f2bf(v.x); o.y = f2bf(v.y); o.z = f2bf(v.z); o.w = f2bf(v.w);
    dst[off] = o;
  } else {
    const int j = i - 798720;  // 0..32767: W_dtT[r*1024+c] = W_dt[c*32+r]
    W_dtT[j] = W_dt[(j & 1023) * 32 + (j >> 10)];
  }
}

// ---------------------------------------------------------------------------
// bf16 MFMA GEMM (NT), 128x128 tile / 256 threads (4 waves x 64x64 quadrant).
// BK=32, LDS +8-short pad (row stride 80 B -> 2-way bank alias, free).
// ---------------------------------------------------------------------------
__global__ __launch_bounds__(256)
void gemm_bf16_128(const short* __restrict__ A, const short* __restrict__ W,
                   float* __restrict__ C, int N, int K) {
  __shared__ short As[128][40];
  __shared__ short Ws[128][40];
  const int tid  = threadIdx.x;
  const int m0   = blockIdx.y * 128;
  const int n0   = blockIdx.x * 128;
  const int lane = tid & 63;
  const int wid  = tid >> 6;
  const int wm   = (wid >> 1) * 64;
  const int wn   = (wid & 1) * 64;
  const int r0   = tid >> 2;
  const int q    = (tid & 3) * 8;
  const int lrow = lane & 15;
  const int lk   = (lane >> 4) * 8;

  f32x4 acc[4][4] = {};

  for (int k0 = 0; k0 < K; k0 += 32) {
    const size_t abase = (size_t)(m0 + r0) * K + k0 + q;
    const uint4 a0v = *reinterpret_cast<const uint4*>(A + abase);
    const uint4 a1v = *reinterpret_cast<const uint4*>(A + abase + (size_t)64 * K);
    const int wr0 = n0 + r0, wr1 = wr0 + 64;
    uint4 w0v = make_uint4(0, 0, 0, 0), w1v = make_uint4(0, 0, 0, 0);
    if (wr0 < N) w0v = *reinterpret_cast<const uint4*>(W + (size_t)wr0 * K + k0 + q);
    if (wr1 < N) w1v = *reinterpret_cast<const uint4*>(W + (size_t)wr1 * K + k0 + q);

    __syncthreads();
    *reinterpret_cast<uint4*>(&As[r0][q])      = a0v;
    *reinterpret_cast<uint4*>(&As[r0 + 64][q]) = a1v;
    *reinterpret_cast<uint4*>(&Ws[r0][q])      = w0v;
    *reinterpret_cast<uint4*>(&Ws[r0 + 64][q]) = w1v;
    __syncthreads();

    bf16x8 af[4], bfr[4];
#pragma unroll
    for (int i = 0; i < 4; ++i)
      af[i] = *reinterpret_cast<const bf16x8*>(&As[wm + i * 16 + lrow][lk]);
#pragma unroll
    for (int j = 0; j < 4; ++j)
      bfr[j] = *reinterpret_cast<const bf16x8*>(&Ws[wn + j * 16 + lrow][lk]);
#pragma unroll
    for (int i = 0; i < 4; ++i)
#pragma unroll
      for (int j = 0; j < 4; ++j)
        acc[i][j] = __builtin_amdgcn_mfma_f32_16x16x32_bf16(af[i], bfr[j],
                                                            acc[i][j], 0, 0, 0);
  }

  const int crow = (lane >> 4) * 4;
  const int ccol = lane & 15;
#pragma unroll
  for (int i = 0; i < 4; ++i) {
#pragma unroll
    for (int j = 0; j < 4; ++j) {
      const int col = n0 + wn + j * 16 + ccol;
      if (col < N) {
        const int row = m0 + wm + i * 16 + crow;
#pragma unroll
        for (int r = 0; r < 4; ++r)
          C[(size_t)(row + r) * N + col] = acc[i][j][r];
      }
    }
  }
}

// ---------------------------------------------------------------------------
// bf16 MFMA GEMM (NT), 64x64 tile / 256 threads (4 waves x 32x32 quadrant).
// ---------------------------------------------------------------------------
__global__ __launch_bounds__(256)
void gemm_bf16_64(const short* __restrict__ A, const short* __restrict__ W,
                  float* __restrict__ C, int N, int K) {
  __shared__ short As[64][40];
  __shared__ short Ws[64][40];
  const int tid  = threadIdx.x;
  const int m0   = blockIdx.y * 64;
  const int n0   = blockIdx.x * 64;
  const int lane = tid & 63;
  const int wid  = tid >> 6;
  const int wm   = (wid >> 1) * 32;
  const int wn   = (wid & 1) * 32;
  const int r0   = tid >> 2;
  const int q    = (tid & 3) * 8;
  const int lrow = lane & 15;
  const int lk   = (lane >> 4) * 8;

  f32x4 acc[2][2] = {};

  for (int k0 = 0; k0 < K; k0 += 32) {
    const uint4 a0v =
        *reinterpret_cast<const uint4*>(A + (size_t)(m0 + r0) * K + k0 + q);
    const int wr0 = n0 + r0;
    uint4 w0v = make_uint4(0, 0, 0, 0);
    if (wr0 < N) w0v = *reinterpret_cast<const uint4*>(W + (size_t)wr0 * K + k0 + q);

    __syncthreads();
    *reinterpret_cast<uint4*>(&As[r0][q]) = a0v;
    *reinterpret_cast<uint4*>(&Ws[r0][q]) = w0v;
    __syncthreads();

    bf16x8 af[2], bfr[2];
#pragma unroll
    for (int i = 0; i < 2; ++i)
      af[i] = *reinterpret_cast<const bf16x8*>(&As[wm + i * 16 + lrow][lk]);
#pragma unroll
    for (int j = 0; j < 2; ++j)
      bfr[j] = *reinterpret_cast<const bf16x8*>(&Ws[wn + j * 16 + lrow][lk]);
#pragma unroll
    for (int i = 0; i < 2; ++i)
#pragma unroll
      for (int j = 0; j < 2; ++j)
        acc[i][j] = __builtin_amdgcn_mfma_f32_16x16x32_bf16(af[i], bfr[j],
                                                            acc[i][j], 0, 0, 0);
  }

  const int crow = (lane >> 4) * 4;
  const int ccol = lane & 15;
#pragma unroll
  for (int i = 0; i < 2; ++i) {
#pragma unroll
    for (int j = 0; j < 2; ++j) {
      const int col = n0 + wn + j * 16 + ccol;
      if (col < N) {
        const int row = m0 + wm + i * 16 + crow;
#pragma unroll
        for (int r = 0; r < 4; ++r)
          C[(size_t)(row + r) * N + col] = acc[i][j][r];
      }
    }
  }
}

// ---------------------------------------------------------------------------
// Causal depthwise conv (K=3) + silu; writes dx.y (f32) and xc_bf (bf16).
// Also applies silu IN-PLACE to the z half: xz[t,1024+c] = silu(...).
// (one thread per element -> no race; removes silu from scan_part3.)
// ---------------------------------------------------------------------------
__global__ __launch_bounds__(256)
void conv_silu_k(float* __restrict__ xz, const float* __restrict__ conv_w,
                 const float* __restrict__ conv_b, float* __restrict__ dxf,
                 short* __restrict__ xcb) {
  const int idx = blockIdx.x * 256 + threadIdx.x;
  const int c = idx & 1023;
  const int t = idx >> 10;
  const int l = t & 1023;
  const float* xp = xz + (size_t)t * 2048 + c;
  float acc = conv_b[c];
  const float w0 = conv_w[c * 3 + 0];
  const float w1 = conv_w[c * 3 + 1];
  const float w2 = conv_w[c * 3 + 2];
  acc += w2 * xp[0];
  if (l >= 1) acc += w1 * xp[-2048];
  if (l >= 2) acc += w0 * xp[-2 * 2048];
  const float v = acc / (1.f + __expf(-acc));
  dxf[2 * (size_t)idx + 1] = v;
  xcb[idx] = f2bf(v);
  // in-place silu on z
  float* zp = xz + (size_t)t * 2048 + 1024 + c;
  const float zv = *zp;
  *zp = zv / (1.f + __expf(-zv));
}

// ---------------------------------------------------------------------------
// pack2: fused delta + scanin-pack + gates.
// ---------------------------------------------------------------------------
__global__ __launch_bounds__(256)
void pack2_k(const float* __restrict__ proj, const float* __restrict__ W_dtT,
             const float* __restrict__ b_dt, float* __restrict__ dxf,
             float4* __restrict__ scanin, float2* __restrict__ gates) {
  const int idx = blockIdx.x * 256 + threadIdx.x;  // 2097152 + 262144
  if (idx < 2097152) {
    const int c = idx & 1023;
    const int t = idx >> 10;
    const float* pr = proj + (size_t)t * 560;
    float acc = b_dt[c];
#pragma unroll
    for (int r = 0; r < 32; ++r) acc = fmaf(pr[r], W_dtT[r * 1024 + c], acc);
    dxf[2 * (size_t)idx] = fmaxf(acc, 0.f) + log1pf(__expf(-fabsf(acc)));
  } else {
    const int j = idx - 2097152;
    const int n = j & 15;
    const int h = (j >> 4) & 7;
    const int t = j >> 7;
    const float* pr = proj + (size_t)t * 560;
    const int hn = h * 16 + n;
    scanin[j] = make_float4(pr[32 + hn], pr[160 + hn], pr[288 + hn], pr[416 + hn]);
    if (n == 0) {
      const float lg = 1.f / (1.f + __expf(-pr[544 + h]));
      const float eg = 1.f / (1.f + __expf(-pr[552 + h]));
      gates[t * 8 + h] = make_float2(1.f - lg, lg * eg);
    }
  }
}

// ---------------------------------------------------------------------------
// Chunked scan.  gid bits: [b:1][chunk:4][h:3][d:7][n:4] -> 524288 threads.
// Step: mag=exp2(dv*Are2); (sn,co)=sincos_rev(dv*AimR); tr=h+betas*bxp;
//       h'=a*tr + gam*bx.
// Depth-2 software pipeline: iteration l issues loads for l+2 (two named
// stage-register sets s0/s1, rotated explicitly).  Final iterations read up
// to 2 rows past each stream; all land inside later d_ws buffers (values
// unused) -- see workspace layout.
// part1 alpha-cumprod via S=sum(dv):  prod alpha = exp2(S*Are2)*cis(S*AimR);
// safe: mag underflows to 0 long before S*AimR leaves sincos range.
// ---------------------------------------------------------------------------
__global__ __launch_bounds__(256)
void scan_part1_k(const float2* __restrict__ dx, const float4* __restrict__ scanin,
                  const float2* __restrict__ gates, const float* __restrict__ A_log,
                  const float* __restrict__ A_imag, float4* __restrict__ csum) {
  const int gid = blockIdx.x * 256 + threadIdx.x;
  const int n  = gid & 15;
  const int d  = (gid >> 4) & 127;
  const int h  = (gid >> 11) & 7;
  const int ck = (gid >> 14) & 15;
  const int b  = gid >> 18;
  const int c  = h * 128 + d;

  const float Are2 = -__expf(A_log[h * 16 + n]) * 1.44269504f;  // *log2(e)
  const float AimR = A_imag[h * 16 + n] * 0.15915494f;          // /(2*pi)

  const int t0 = b * 1024 + ck * 64;
  float bxpr = 0.f, bxpi = 0.f;
  if (ck > 0) {
    const float xv = dx[(size_t)(t0 - 1) * 1024 + c].y;
    const float2 bp =
        reinterpret_cast<const float2*>(scanin)[2 * ((size_t)(t0 - 1) * 128 + h * 16 + n)];
    bxpr = xv * bp.x; bxpi = xv * bp.y;
  }

  const float2* dxp = dx + (size_t)t0 * 1024 + c;
  const float2* sp  = reinterpret_cast<const float2*>(scanin) +
                      2 * ((size_t)t0 * 128 + h * 16 + n);
  const float2* gp  = gates + (size_t)t0 * 8 + h;

  // prologue: stage l=0 and l=1
  float2 dxv0 = dxp[0],    dxv1 = dxp[1024];
  float2 bc0  = sp[0],     bc1  = sp[256];
  float2 bg0  = gp[0],     bg1  = gp[8];
  dxp += 2048; sp += 512; gp += 16;

  float S = 0.f, hr = 0.f, hi = 0.f;
  for (int l = 0; l < 64; ++l) {
    const float2 dxv_n = *dxp;   // load l+2
    const float2 bc_n  = *sp;
    const float2 bg_n  = *gp;
    dxp += 1024; sp += 256; gp += 8;

    const float dv = dxv0.x, xv = dxv0.y;
    const float betas = dv * bg0.x;
    const float gam   = dv * bg0.y;
    const float mag = fexp2(dv * Are2);
    const float rev = dv * AimR;
    const float sn = fsin_rev(rev), co = fcos_rev(rev);
    const float are = mag * co, aim = mag * sn;
    const float bxr = xv * bc0.x, bxi = xv * bc0.y;
    const float tr = fmaf(betas, bxpr, hr);
    const float ti = fmaf(betas, bxpi, hi);
    hr = fmaf(are, tr, fmaf(-aim, ti, gam * bxr));
    hi = fmaf(are, ti, fmaf(aim, tr, gam * bxi));
    bxpr = bxr; bxpi = bxi;
    S += dv;

    dxv0 = dxv1; bc0 = bc1; bg0 = bg1;
    dxv1 = dxv_n; bc1 = bc_n; bg1 = bg_n;
  }
  const float Amag = fexp2(S * Are2);
  const float Arev = S * AimR;
  csum[gid] = make_float4(Amag * fcos_rev(Arev), Amag * fsin_rev(Arev), hr, hi);
}

__global__ __launch_bounds__(256)
void scan_part2_k(const float4* __restrict__ csum, float2* __restrict__ hstart) {
  const int gid = blockIdx.x * 256 + threadIdx.x;  // 32768 total
  const int low = gid & 2047;
  const int h   = (gid >> 11) & 7;
  const int b   = gid >> 14;
  float hr = 0.f, hi = 0.f;
#pragma unroll
  for (int ck = 0; ck < 16; ++ck) {
    const int s = (((b * 16 + ck) * 8 + h) << 11) + low;
    hstart[s] = make_float2(hr, hi);
    const float4 cs = csum[s];
    const float nhr = cs.x * hr - cs.y * hi + cs.z;
    const float nhi = cs.x * hi + cs.y * hr + cs.w;
    hr = nhr; hi = nhi;
  }
}

__global__ __launch_bounds__(256)
void scan_part3_k(const float* __restrict__ gz, const float2* __restrict__ dx,
                  const float4* __restrict__ scanin, const float2* __restrict__ gates,
                  const float* __restrict__ A_log, const float* __restrict__ A_imag,
                  const float* __restrict__ D_param,
                  const float2* __restrict__ hstart, short* __restrict__ ygb) {
  const int gid = blockIdx.x * 256 + threadIdx.x;
  const int n  = gid & 15;
  const int d  = (gid >> 4) & 127;
  const int h  = (gid >> 11) & 7;
  const int ck = (gid >> 14) & 15;
  const int b  = gid >> 18;
  const int c  = h * 128 + d;

  const float Are2 = -__expf(A_log[h * 16 + n]) * 1.44269504f;
  const float AimR = A_imag[h * 16 + n] * 0.15915494f;
  const float Dc   = D_param[c];

  const int t0 = b * 1024 + ck * 64;
  float bxpr = 0.f, bxpi = 0.f;
  if (ck > 0) {
    const float xv = dx[(size_t)(t0 - 1) * 1024 + c].y;
    const float2 bp =
        reinterpret_cast<const float2*>(scanin)[2 * ((size_t)(t0 - 1) * 128 + h * 16 + n)];
    bxpr = xv * bp.x; bxpi = xv * bp.y;
  }
  const float2 h0 = hstart[gid];
  float hr = h0.x, hi = h0.y;

  const float2* dxp = dx + (size_t)t0 * 1024 + c;
  const float4* sp  = scanin + (size_t)t0 * 128 + h * 16 + n;
  const float2* gp  = gates + (size_t)t0 * 8 + h;
  const float*  zp  = gz + (size_t)t0 * 2048 + 1024 + c;  // pre-silu'd
  short*        yp  = ygb + (size_t)t0 * 1024 + c;

  // prologue: stage l=0 and l=1
  float2 dxv0 = dxp[0],   dxv1 = dxp[1024];
  float4 bc0  = sp[0],    bc1  = sp[128];
  float2 bg0  = gp[0],    bg1  = gp[8];
  float  zv0  = zp[0],    zv1  = zp[2048];
  dxp += 2048; sp += 256; gp += 16; zp += 4096;

  for (int l = 0; l < 64; ++l) {
    const float2 dxv_n = *dxp;   // load l+2
    const float4 bc_n  = *sp;
    const float2 bg_n  = *gp;
    const float  zv_n  = *zp;
    dxp += 1024; sp += 128; gp += 8; zp += 2048;

    const float dv = dxv0.x, xv = dxv0.y;
    const float betas = dv * bg0.x;
    const float gam   = dv * bg0.y;
    const float mag = fexp2(dv * Are2);
    const float rev = dv * AimR;
    const float sn = fsin_rev(rev), co = fcos_rev(rev);
    const float are = mag * co, aim = mag * sn;
    const float bxr = xv * bc0.x, bxi = xv * bc0.y;
    const float tr = fmaf(betas, bxpr, hr);
    const float ti = fmaf(betas, bxpi, hi);
    hr = fmaf(are, tr, fmaf(-aim, ti, gam * bxr));
    hi = fmaf(are, ti, fmaf(aim, tr, gam * bxi));
    bxpr = bxr; bxpi = bxi;

    float y = fmaf(hr, bc0.z, hi * bc0.w);
    ROR_ADD(y, 0x121)  // row_ror:1
    ROR_ADD(y, 0x122)  // row_ror:2
    ROR_ADD(y, 0x124)  // row_ror:4
    ROR_ADD(y, 0x128)  // row_ror:8  -> all 16 lanes hold the n-sum

    const short yo = f2bf(fmaf(Dc, xv, y) * zv0);  // zv0 = silu(z) precomputed
    if (n == 0) *yp = yo;
    yp += 1024;

    dxv0 = dxv1; bc0 = bc1; bg0 = bg1; zv0 = zv1;
    dxv1 = dxv_n; bc1 = bc_n; bg1 = bg_n; zv1 = zv_n;
  }
}

// ---------------------------------------------------------------------------
extern "C" void kernel_launch(void* const* d_in, const int* in_sizes, int n_in,
                              void* d_out, int out_size, void* d_ws, size_t ws_size,
                              hipStream_t stream) {
  (void)in_sizes; (void)n_in; (void)out_size; (void)ws_size;
  const float* x       = (const float*)d_in[0];
  const float* W_in    = (const float*)d_in[1];
  const float* conv_w  = (const float*)d_in[2];
  const float* conv_b  = (const float*)d_in[3];
  const float* W_x     = (const float*)d_in[4];
  const float* W_dt    = (const float*)d_in[5];
  const float* b_dt    = (const float*)d_in[6];
  const float* A_log   = (const float*)d_in[7];
  const float* A_imag  = (const float*)d_in[8];
  const float* D_param = (const float*)d_in[9];
  const float* W_out   = (const float*)d_in[10];
  float* out = (float*)d_out;

  // workspace layout (float offsets); total 15,106,048 floats = 57.6 MiB.
  // Aliases (disjoint lifetimes): x_bf/win_bf/xc_bf live inside csum's slot
  // (all dead before part1 writes csum); wx_bf/wdtT inside hst's slot (dead
  // before part2 writes hst).  Scan depth-2 prefetch overreads <=2 rows past
  // dx / scanin / gates / xz -- all land in subsequent ws buffers (allocated).
  float* ws = (float*)d_ws;
  float*  xz      = ws;                          // 4,194,304
  float*  proj    = ws + 4194304;                // 1,146,880
  float2* dx      = (float2*)(ws + 5341184);     // 4,194,304 (2M float2)
  float4* scanin  = (float4*)(ws + 9535488);     // 1,048,576
  float2* gates   = (float2*)(ws + 10584064);    //    65,536
  short*  yg_bf   = (short*)(ws + 10649600);     // 1,048,576 (2M shorts)
  short*  wout_bf = (short*)(ws + 11698176);     //   262,144
  float4* csum    = (float4*)(ws + 11960320);    // 2,097,152
  short*  x_bf    = (short*)(ws + 11960320);     //   [alias in csum]
  short*  win_bf  = (short*)(ws + 12484608);     //   [alias in csum]
  short*  xc_bf   = (short*)(ws + 13008896);     //   [alias in csum]
  float2* hst     = (float2*)(ws + 14057472);    // 1,048,576
  short*  wx_bf   = (short*)(ws + 14057472);     //   [alias in hst]
  float*  wdtT    = ws + 14344192;               //   [alias in hst]

  // 0) conversions + W_dt transpose (one kernel)
  cvt_all_k<<<dim3(3248), dim3(256), 0, stream>>>(x, W_in, W_x, W_out, W_dt,
                                                  x_bf, win_bf, wx_bf, wout_bf,
                                                  wdtT);
  // 1) xz = x @ W_in^T        (M=2048, N=2048, K=512)
  gemm_bf16_128<<<dim3(16, 16), dim3(256), 0, stream>>>(x_bf, win_bf, xz, 2048, 512);
  // 2) dx.y = silu(dwconv(x_proj)) (+ bf16 copy); in-place silu on z half
  conv_silu_k<<<dim3(8192), dim3(256), 0, stream>>>(xz, conv_w, conv_b,
                                                    (float*)dx, xc_bf);
  // 3) proj = xc @ W_x^T      (M=2048, N=560, K=1024)
  gemm_bf16_64<<<dim3(9, 32), dim3(256), 0, stream>>>(xc_bf, wx_bf, proj, 560, 1024);
  // 4) dx.x = delta; scanin/gates pack
  pack2_k<<<dim3(9216), dim3(256), 0, stream>>>(proj, wdtT, b_dt, (float*)dx,
                                                scanin, gates);
  // 5) chunked scan (depth-2 pipelined)
  scan_part1_k<<<dim3(2048), dim3(256), 0, stream>>>(dx, scanin, gates, A_log,
                                                     A_imag, csum);
  scan_part2_k<<<dim3(128), dim3(256), 0, stream>>>(csum, hst);
  scan_part3_k<<<dim3(2048), dim3(256), 0, stream>>>(xz, dx, scanin, gates, A_log,
                                                     A_imag, D_param, hst, yg_bf);
  // 6) out = yg_bf @ W_out^T  (M=2048, N=512, K=1024)
  gemm_bf16_64<<<dim3(8, 32), dim3(256), 0, stream>>>(yg_bf, wout_bf, out, 512, 1024);
}